// Round 15
// baseline (2074.554 us; speedup 1.0000x reference)
//
#include <hip/hip_runtime.h>
#include <math.h>

#define NN 100000
#define NE 3200000
#define FD 256        // feature dim
#define NC 40         // classes
#define BN_BUCK 196   // ceil(NN / 512)

typedef unsigned int u32;
typedef __attribute__((ext_vector_type(8))) short short8;
typedef __attribute__((ext_vector_type(4))) float f32x4;

#define AS1 __attribute__((address_space(1)))
#define AS3 __attribute__((address_space(3)))

static __device__ __forceinline__ float bf2f(unsigned short h) {
    return __builtin_bit_cast(float, ((u32)h) << 16);
}
static __device__ __forceinline__ unsigned short f2bf(float f) {
    u32 u = __builtin_bit_cast(u32, f);
    u += 0x7fffu + ((u >> 16) & 1u);   // RNE
    return (unsigned short)(u >> 16);
}

// ---------------- binned CSR build ----------------

__global__ __launch_bounds__(256) void bucket_count(const int* __restrict__ ei_dst, int* __restrict__ gcount) {
    __shared__ int sh[BN_BUCK];
    int t = threadIdx.x;
    if (t < BN_BUCK) sh[t] = 0;
    __syncthreads();
    int i = blockIdx.x * 1024 + t * 4;
    int4 d = *reinterpret_cast<const int4*>(ei_dst + i);
    atomicAdd(&sh[d.x >> 9], 1);
    atomicAdd(&sh[d.y >> 9], 1);
    atomicAdd(&sh[d.z >> 9], 1);
    atomicAdd(&sh[d.w >> 9], 1);
    __syncthreads();
    if (t < BN_BUCK && sh[t]) atomicAdd(&gcount[t], sh[t]);
}

__global__ __launch_bounds__(256) void bucket_scan(const int* __restrict__ gcount,
                                                   int* __restrict__ bucketBase,
                                                   int* __restrict__ bucketFill,
                                                   int* __restrict__ row_ptr) {
    __shared__ int s[256];
    int t = threadIdx.x;
    int v = (t < BN_BUCK) ? gcount[t] : 0;
    s[t] = v;
    __syncthreads();
    for (int d = 1; d < 256; d <<= 1) {
        int x = (t >= d) ? s[t - d] : 0;
        __syncthreads();
        s[t] += x;
        __syncthreads();
    }
    int excl = s[t] - v;
    if (t < BN_BUCK) {
        bucketBase[t] = excl;
        bucketFill[t] = excl;
    }
    if (t == 0) {
        bucketBase[BN_BUCK] = NE;
        row_ptr[NN] = NE;
    }
}

__global__ __launch_bounds__(256) void partition_edges(const int* __restrict__ ei, const float* __restrict__ ev,
                                                       int* __restrict__ bucketFill, int2* __restrict__ ebuf) {
    __shared__ int cnt[BN_BUCK];
    __shared__ int gb[BN_BUCK];
    __shared__ int fill[BN_BUCK];
    int t = threadIdx.x;
    if (t < BN_BUCK) { cnt[t] = 0; fill[t] = 0; }
    __syncthreads();
    int i = blockIdx.x * 1024 + t * 4;
    int4 s4 = *reinterpret_cast<const int4*>(ei + i);
    int4 d4 = *reinterpret_cast<const int4*>(ei + NE + i);
    float4 v4 = *reinterpret_cast<const float4*>(ev + i);
    int b0 = d4.x >> 9, b1 = d4.y >> 9, b2 = d4.z >> 9, b3 = d4.w >> 9;
    atomicAdd(&cnt[b0], 1);
    atomicAdd(&cnt[b1], 1);
    atomicAdd(&cnt[b2], 1);
    atomicAdd(&cnt[b3], 1);
    __syncthreads();
    if (t < BN_BUCK && cnt[t]) gb[t] = atomicAdd(&bucketFill[t], cnt[t]);
    __syncthreads();
    int r;
    r = atomicAdd(&fill[b0], 1); ebuf[gb[b0] + r] = make_int2((s4.x << 9) | (d4.x & 511), __float_as_int(v4.x));
    r = atomicAdd(&fill[b1], 1); ebuf[gb[b1] + r] = make_int2((s4.y << 9) | (d4.y & 511), __float_as_int(v4.y));
    r = atomicAdd(&fill[b2], 1); ebuf[gb[b2] + r] = make_int2((s4.z << 9) | (d4.z & 511), __float_as_int(v4.z));
    r = atomicAdd(&fill[b3], 1); ebuf[gb[b3] + r] = make_int2((s4.w << 9) | (d4.w & 511), __float_as_int(v4.w));
}

// 512 threads: one thread per bucket-node; count -> 512-wide scan -> place
__global__ __launch_bounds__(512) void bucket_csr(const int* __restrict__ bucketBase,
                                                  const int2* __restrict__ ebuf,
                                                  int* __restrict__ row_ptr, int2* __restrict__ cp) {
    __shared__ int cnt[512];
    __shared__ int s[512];
    int b = blockIdx.x, t = threadIdx.x;
    int beg = bucketBase[b], end = bucketBase[b + 1];
    cnt[t] = 0;
    __syncthreads();
    for (int e = beg + t; e < end; e += 512)
        atomicAdd(&cnt[ebuf[e].x & 511], 1);
    __syncthreads();
    int c = cnt[t];
    s[t] = c;
    __syncthreads();
    for (int d = 1; d < 512; d <<= 1) {
        int x = (t >= d) ? s[t - d] : 0;
        __syncthreads();
        s[t] += x;
        __syncthreads();
    }
    int excl = s[t] - c;
    int g = b * 512 + t;
    if (g < NN) row_ptr[g] = beg + excl;
    __syncthreads();
    cnt[t] = excl;
    __syncthreads();
    for (int e = beg + t; e < end; e += 512) {
        int2 E = ebuf[e];
        int r = atomicAdd(&cnt[E.x & 511], 1);
        cp[beg + r] = make_int2(E.x >> 9, E.y);
    }
}

// ---------------- weight prep + x quantization ----------------

__global__ __launch_bounds__(256) void prep_w(const float* __restrict__ W1,
                                              const float* __restrict__ W2,
                                              const float* __restrict__ W3,
                                              unsigned short* __restrict__ Wt1,
                                              unsigned short* __restrict__ Wt2,
                                              unsigned short* __restrict__ Wt3p) {
    int b = blockIdx.x, t = threadIdx.x;
    if (b < 256) {
        Wt1[b * 256 + t] = f2bf(W1[t * 256 + b]);
    } else if (b < 512) {
        int n = b - 256;
        Wt2[n * 256 + t] = f2bf(W2[t * 256 + n]);
    } else {
        int n = b - 512;
        Wt3p[n * 256 + t] = (n < NC) ? f2bf(W3[t * NC + n]) : (unsigned short)0;
    }
}

__global__ __launch_bounds__(256) void quant_x(const float* __restrict__ X,
                                               u32* __restrict__ Q, float* __restrict__ Sc) {
    int wv = threadIdx.x >> 6, l = threadIdx.x & 63;
    int row = blockIdx.x * 4 + wv;
    float4 v = reinterpret_cast<const float4*>(X)[(size_t)row * 64 + l];
    float m = fmaxf(fmaxf(fabsf(v.x), fabsf(v.y)), fmaxf(fabsf(v.z), fabsf(v.w)));
    for (int d = 32; d > 0; d >>= 1) m = fmaxf(m, __shfl_xor(m, d));
    float inv = (m > 0.f) ? 127.f / m : 0.f;
    int q0 = (int)rintf(v.x * inv), q1 = (int)rintf(v.y * inv);
    int q2 = (int)rintf(v.z * inv), q3 = (int)rintf(v.w * inv);
    u32 pk = (u32)(q0 & 255) | ((u32)(q1 & 255) << 8) | ((u32)(q2 & 255) << 16) | ((u32)(q3 & 255) << 24);
    Q[(size_t)row * 64 + l] = pk;
    if (l == 0) Sc[row] = m * (1.f / 127.f);
}

__global__ __launch_bounds__(256) void quant_h(const unsigned short* __restrict__ H,
                                               u32* __restrict__ Q, float* __restrict__ Sc) {
    int wv = threadIdx.x >> 6, l = threadIdx.x & 63;
    int row = blockIdx.x * 4 + wv;
    ushort4 hv = reinterpret_cast<const ushort4*>(H)[(size_t)row * 64 + l];
    float v0 = bf2f(hv.x), v1 = bf2f(hv.y), v2 = bf2f(hv.z), v3 = bf2f(hv.w);
    float m = fmaxf(fmaxf(v0, v1), fmaxf(v2, v3));
    for (int d = 32; d > 0; d >>= 1) m = fmaxf(m, __shfl_xor(m, d));
    float inv = (m > 0.f) ? 255.f / m : 0.f;
    int q0 = (int)rintf(v0 * inv), q1 = (int)rintf(v1 * inv);
    int q2 = (int)rintf(v2 * inv), q3 = (int)rintf(v3 * inv);
    u32 pk = (u32)(q0 & 255) | ((u32)(q1 & 255) << 8) | ((u32)(q2 & 255) << 16) | ((u32)(q3 & 255) << 24);
    Q[(size_t)row * 64 + l] = pk;
    if (l == 0) Sc[row] = m * (1.f / 255.f);
}

// ------- SPMM int8 PAIRED: lanes 0-31 gather edge a, lanes 32-63 edge b (uint2 = 8 feats/lane).
//         Named accumulators a0..a7 (r12 lesson: NO runtime-indexed arrays). -------

template <int UNSIGNED>
__global__ __launch_bounds__(256) void spmm_i8(const int* __restrict__ rp,
                                               const int2* __restrict__ cp,
                                               const u32* __restrict__ Q,
                                               const float* __restrict__ Sc,
                                               unsigned short* __restrict__ O) {
    int wv = threadIdx.x >> 6;
    int l = threadIdx.x & 63;
    int lh = l & 31;
    int hi = l >> 5;                 // 0 for lanes 0-31, 1 for lanes 32-63
    int row = blockIdx.x * 4 + wv;
    if (row >= NN) return;
    int beg = __builtin_amdgcn_readfirstlane(rp[row]);
    int end = __builtin_amdgcn_readfirstlane(rp[row + 1]);
    const uint2* __restrict__ Q2 = reinterpret_cast<const uint2*>(Q);
    float a0 = 0.f, a1 = 0.f, a2 = 0.f, a3 = 0.f, a4 = 0.f, a5 = 0.f, a6 = 0.f, a7 = 0.f;

#define ACCP(QQ, V)                                                              \
    {                                                                            \
        u32 qx_ = (QQ).x, qy_ = (QQ).y;                                          \
        float v_ = (V);                                                          \
        if (UNSIGNED) {                                                          \
            a0 += v_ * (float)(qx_ & 255u);                                      \
            a1 += v_ * (float)((qx_ >> 8) & 255u);                               \
            a2 += v_ * (float)((qx_ >> 16) & 255u);                              \
            a3 += v_ * (float)(qx_ >> 24);                                       \
            a4 += v_ * (float)(qy_ & 255u);                                      \
            a5 += v_ * (float)((qy_ >> 8) & 255u);                               \
            a6 += v_ * (float)((qy_ >> 16) & 255u);                              \
            a7 += v_ * (float)(qy_ >> 24);                                       \
        } else {                                                                 \
            a0 += v_ * (float)(int)(char)(qx_);                                  \
            a1 += v_ * (float)(int)(char)(qx_ >> 8);                             \
            a2 += v_ * (float)(int)(char)(qx_ >> 16);                            \
            a3 += v_ * (float)(int)(char)(qx_ >> 24);                            \
            a4 += v_ * (float)(int)(char)(qy_);                                  \
            a5 += v_ * (float)(int)(char)(qy_ >> 8);                             \
            a6 += v_ * (float)(int)(char)(qy_ >> 16);                            \
            a7 += v_ * (float)(int)(char)(qy_ >> 24);                            \
        }                                                                        \
    }

    int e = beg;
    int efull = beg + ((end - beg) & ~15);
    if (e < efull) {
        int2 m[16];
        float vs[16];
#pragma unroll
        for (int j = 0; j < 16; ++j) m[j] = cp[e + j];
#pragma unroll
        for (int j = 0; j < 16; ++j) vs[j] = __int_as_float(m[j].y) * Sc[m[j].x];
        e += 16;
        for (; e < efull; e += 16) {
            uint2 q[8];
#pragma unroll
            for (int p = 0; p < 8; ++p) {        // 8 paired gathers (16 edges) in flight
                int s = hi ? m[2 * p + 1].x : m[2 * p].x;
                q[p] = Q2[(size_t)s * 32 + lh];
            }
            int2 mn[16];
            float vsn[16];
#pragma unroll
            for (int j = 0; j < 16; ++j) mn[j] = cp[e + j];
#pragma unroll
            for (int j = 0; j < 16; ++j) vsn[j] = __int_as_float(mn[j].y) * Sc[mn[j].x];
#pragma unroll
            for (int p = 0; p < 8; ++p) {
                float v = hi ? vs[2 * p + 1] : vs[2 * p];
                ACCP(q[p], v);
            }
#pragma unroll
            for (int j = 0; j < 16; ++j) { m[j] = mn[j]; vs[j] = vsn[j]; }
        }
        {
            uint2 q[8];
#pragma unroll
            for (int p = 0; p < 8; ++p) {
                int s = hi ? m[2 * p + 1].x : m[2 * p].x;
                q[p] = Q2[(size_t)s * 32 + lh];
            }
#pragma unroll
            for (int p = 0; p < 8; ++p) {
                float v = hi ? vs[2 * p + 1] : vs[2 * p];
                ACCP(q[p], v);
            }
        }
    }
    if (end - e >= 8) {                          // paired depth-8 tail (4 pairs)
        int2 m[8];
        float vs[8];
#pragma unroll
        for (int j = 0; j < 8; ++j) m[j] = cp[e + j];
#pragma unroll
        for (int j = 0; j < 8; ++j) vs[j] = __int_as_float(m[j].y) * Sc[m[j].x];
        uint2 q[4];
#pragma unroll
        for (int p = 0; p < 4; ++p) {
            int s = hi ? m[2 * p + 1].x : m[2 * p].x;
            q[p] = Q2[(size_t)s * 32 + lh];
        }
#pragma unroll
        for (int p = 0; p < 4; ++p) {
            float v = hi ? vs[2 * p + 1] : vs[2 * p];
            ACCP(q[p], v);
        }
        e += 8;
    }
    if (end - e >= 4) {                          // paired depth-4 tail (2 pairs)
        int2 m[4];
        float vs[4];
#pragma unroll
        for (int j = 0; j < 4; ++j) m[j] = cp[e + j];
#pragma unroll
        for (int j = 0; j < 4; ++j) vs[j] = __int_as_float(m[j].y) * Sc[m[j].x];
        uint2 q[2];
#pragma unroll
        for (int p = 0; p < 2; ++p) {
            int s = hi ? m[2 * p + 1].x : m[2 * p].x;
            q[p] = Q2[(size_t)s * 32 + lh];
        }
#pragma unroll
        for (int p = 0; p < 2; ++p) {
            float v = hi ? vs[2 * p + 1] : vs[2 * p];
            ACCP(q[p], v);
        }
        e += 4;
    }
    for (; e < end; ++e) {                       // serial tail: both halves load same row, hi masked
        int2 m1 = cp[e];
        float vsv = __int_as_float(m1.y) * Sc[m1.x];
        float v = hi ? 0.f : vsv;
        uint2 q1 = Q2[(size_t)m1.x * 32 + lh];
        ACCP(q1, v);
    }
#undef ACCP
    // combine halves (named scalars -> plain ds_bpermute, no arrays)
    a0 += __shfl_xor(a0, 32);
    a1 += __shfl_xor(a1, 32);
    a2 += __shfl_xor(a2, 32);
    a3 += __shfl_xor(a3, 32);
    a4 += __shfl_xor(a4, 32);
    a5 += __shfl_xor(a5, 32);
    a6 += __shfl_xor(a6, 32);
    a7 += __shfl_xor(a7, 32);
    if (!hi) {
        short8 ov;
        ov[0] = (short)f2bf(a0);
        ov[1] = (short)f2bf(a1);
        ov[2] = (short)f2bf(a2);
        ov[3] = (short)f2bf(a3);
        ov[4] = (short)f2bf(a4);
        ov[5] = (short)f2bf(a5);
        ov[6] = (short)f2bf(a6);
        ov[7] = (short)f2bf(a7);
        *reinterpret_cast<short8*>(O + (size_t)row * 256 + lh * 8) = ov;
    }
}

// ---------------- MFMA GEMM (r9-proven): BM=128, BN=128, relu, out bf16 ----------------

#define BM 128
#define BKK 64

__global__ __launch_bounds__(256) void gemm_mfma(const unsigned short* __restrict__ A,
                                                 const unsigned short* __restrict__ Wt,
                                                 unsigned short* __restrict__ C, int M, int relu) {
    __shared__ unsigned short As[BM * BKK];
    __shared__ unsigned short Bs[BM * BKK];
    int tid = threadIdx.x;
    int l = tid & 63;
    int w = tid >> 6;
    int wm = w >> 1, wn = w & 1;
    int bm = blockIdx.x * BM;
    int bn = blockIdx.y * BM;

    f32x4 acc[4][4] = {};

    for (int kt = 0; kt < 4; ++kt) {
        int k0 = kt * BKK;
#pragma unroll
        for (int i = 0; i < 4; ++i) {
            int e = i * 256 + tid;
            int row = e >> 3;
            int c = e & 7;
            int cs = c ^ (row & 7);
            int ga = min(bm + row, M - 1);
            __builtin_amdgcn_global_load_lds(
                (const AS1 u32*)(A + (size_t)ga * 256 + k0 + cs * 8),
                (AS3 u32*)(As + e * 8), 16, 0, 0);
            __builtin_amdgcn_global_load_lds(
                (const AS1 u32*)(Wt + (size_t)(bn + row) * 256 + k0 + cs * 8),
                (AS3 u32*)(Bs + e * 8), 16, 0, 0);
        }
        __syncthreads();
#pragma unroll
        for (int h = 0; h < 2; ++h) {
            short8 av[4], bv[4];
#pragma unroll
            for (int m = 0; m < 4; ++m) {
                int row = wm * 64 + m * 16 + (l & 15);
                int cs = (h * 4 + (l >> 4)) ^ (row & 7);
                av[m] = *(const short8*)(As + row * BKK + cs * 8);
            }
#pragma unroll
            for (int n = 0; n < 4; ++n) {
                int row = wn * 64 + n * 16 + (l & 15);
                int cs = (h * 4 + (l >> 4)) ^ (row & 7);
                bv[n] = *(const short8*)(Bs + row * BKK + cs * 8);
            }
#pragma unroll
            for (int m = 0; m < 4; ++m)
#pragma unroll
                for (int n = 0; n < 4; ++n)
                    acc[m][n] = __builtin_amdgcn_mfma_f32_16x16x32_bf16(av[m], bv[n], acc[m][n], 0, 0, 0);
        }
        __syncthreads();
    }

#pragma unroll
    for (int m = 0; m < 4; ++m)
#pragma unroll
        for (int r = 0; r < 4; ++r) {
            int gr = bm + wm * 64 + m * 16 + (l >> 4) * 4 + r;
            if (gr >= M) continue;
#pragma unroll
            for (int n = 0; n < 4; ++n) {
                int gc = bn + wn * 64 + n * 16 + (l & 15);
                float v = acc[m][n][r];
                if (relu) v = fmaxf(v, 0.f);
                C[(size_t)gr * 256 + gc] = f2bf(v);
            }
        }
}

// ------- GEMM3 (r9-proven): Lb[M,40](bf16) = H2[M,256](bf16) @ Wt3p[48][256](bf16) -------

__global__ __launch_bounds__(256) void gemm3_mfma(const unsigned short* __restrict__ H2,
                                                  const unsigned short* __restrict__ Wt3p,
                                                  unsigned short* __restrict__ Lb) {
    int tid = threadIdx.x, l = tid & 63, w = tid >> 6;
    int row0 = blockIdx.x * 64 + w * 16;
    f32x4 acc[3] = {};
    int ra = min(row0 + (l & 15), NN - 1);
    const unsigned short* ap = H2 + (size_t)ra * 256 + (l >> 4) * 8;
#pragma unroll
    for (int kt = 0; kt < 8; ++kt) {
        short8 av = *(const short8*)(ap + kt * 32);
#pragma unroll
        for (int j = 0; j < 3; ++j) {
            const unsigned short* bp = Wt3p + (size_t)(j * 16 + (l & 15)) * 256 + kt * 32 + (l >> 4) * 8;
            short8 bv = *(const short8*)bp;
            acc[j] = __builtin_amdgcn_mfma_f32_16x16x32_bf16(av, bv, acc[j], 0, 0, 0);
        }
    }
#pragma unroll
    for (int j = 0; j < 3; ++j)
#pragma unroll
        for (int r = 0; r < 4; ++r) {
            int gr = row0 + (l >> 4) * 4 + r;
            int gc = j * 16 + (l & 15);
            if (gr < NN && gc < NC) Lb[(size_t)gr * NC + gc] = f2bf(acc[j][r]);
        }
}

// ------- fused: out[row] = log_softmax( sum_e val * Lb[src] ), depth 16 + 8 + 4 tails -------

__global__ __launch_bounds__(256) void spmm40_lsm(const int* __restrict__ rp,
                                                  const int2* __restrict__ cp,
                                                  const unsigned short* __restrict__ Lb,
                                                  float* __restrict__ out) {
    int wv = threadIdx.x >> 6, l = threadIdx.x & 63;
    int row = blockIdx.x * 4 + wv;
    if (row >= NN) return;
    int beg = __builtin_amdgcn_readfirstlane(rp[row]);
    int end = __builtin_amdgcn_readfirstlane(rp[row + 1]);
    int lc = min(l, NC - 1);
    float acc = 0.f;
    int e = beg;
    int efull = beg + ((end - beg) & ~15);
    if (e < efull) {
        int2 m[16];
#pragma unroll
        for (int j = 0; j < 16; ++j) m[j] = cp[e + j];
        e += 16;
        for (; e < efull; e += 16) {
            unsigned short hv[16];
#pragma unroll
            for (int j = 0; j < 16; ++j) hv[j] = Lb[(size_t)m[j].x * NC + lc];
            int2 mn[16];
#pragma unroll
            for (int j = 0; j < 16; ++j) mn[j] = cp[e + j];
#pragma unroll
            for (int j = 0; j < 16; ++j)
                acc += __int_as_float(m[j].y) * bf2f(hv[j]);
#pragma unroll
            for (int j = 0; j < 16; ++j) m[j] = mn[j];
        }
        {
            unsigned short hv[16];
#pragma unroll
            for (int j = 0; j < 16; ++j) hv[j] = Lb[(size_t)m[j].x * NC + lc];
#pragma unroll
            for (int j = 0; j < 16; ++j)
                acc += __int_as_float(m[j].y) * bf2f(hv[j]);
        }
    }
    if (end - e >= 8) {
        int2 m[8];
#pragma unroll
        for (int j = 0; j < 8; ++j) m[j] = cp[e + j];
        unsigned short hv[8];
#pragma unroll
        for (int j = 0; j < 8; ++j) hv[j] = Lb[(size_t)m[j].x * NC + lc];
#pragma unroll
        for (int j = 0; j < 8; ++j)
            acc += __int_as_float(m[j].y) * bf2f(hv[j]);
        e += 8;
    }
    if (end - e >= 4) {
        int2 m[4];
#pragma unroll
        for (int j = 0; j < 4; ++j) m[j] = cp[e + j];
        unsigned short hv[4];
#pragma unroll
        for (int j = 0; j < 4; ++j) hv[j] = Lb[(size_t)m[j].x * NC + lc];
#pragma unroll
        for (int j = 0; j < 4; ++j)
            acc += __int_as_float(m[j].y) * bf2f(hv[j]);
        e += 4;
    }
    for (; e < end; ++e) {
        int2 m1 = cp[e];
        acc += __int_as_float(m1.y) * bf2f(Lb[(size_t)m1.x * NC + lc]);
    }
    float v = (l < NC) ? acc : -INFINITY;
    float mx = v;
    for (int d = 32; d > 0; d >>= 1) mx = fmaxf(mx, __shfl_xor(mx, d));
    float ex = (l < NC) ? expf(v - mx) : 0.f;
    float ssum = ex;
    for (int d = 32; d > 0; d >>= 1) ssum += __shfl_xor(ssum, d);
    float ls = logf(ssum);
    if (l < NC) out[(size_t)row * NC + l] = v - mx - ls;
}

// ---------------- launch ----------------

extern "C" void kernel_launch(void* const* d_in, const int* in_sizes, int n_in,
                              void* d_out, int out_size, void* d_ws, size_t ws_size,
                              hipStream_t stream) {
    const float* x  = (const float*)d_in[0];
    const int*   ei = (const int*)d_in[1];
    const float* ev = (const float*)d_in[2];
    const float* W1 = (const float*)d_in[3];
    const float* W2 = (const float*)d_in[4];
    const float* W3 = (const float*)d_in[5];
    float* out = (float*)d_out;

    char* ws = (char*)d_ws;
    size_t o = 0;
    unsigned short* B0 = (unsigned short*)(ws + o); o += (size_t)NN * FD * 2;   // 51.2 MB (h1/h2)
    unsigned short* B1 = (unsigned short*)(ws + o); o += (size_t)NN * FD * 2;   // 51.2 MB agg (aliases ebuf)
    u32*   Q8          = (u32*)(ws + o);            o += (size_t)NN * FD;       // 25.6 MB int8 table
    float* Sc          = (float*)(ws + o);          o += (size_t)NN * 4;        // 400 KB scales
    unsigned short* Lb = (unsigned short*)(ws + o); o += (size_t)NN * NC * 2;   // 8 MB
    int2*  cp          = (int2*)(ws + o);           o += (size_t)NE * 8;        // 25.6 MB
    int*   row_ptr     = (int*)(ws + o);            o += 400128;
    int*   gcount      = (int*)(ws + o);            o += 1024;
    int*   bucketBase  = (int*)(ws + o);            o += 1024;
    int*   bucketFill  = (int*)(ws + o);            o += 1024;
    unsigned short* Wt1  = (unsigned short*)(ws + o); o += 256 * 256 * 2;
    unsigned short* Wt2  = (unsigned short*)(ws + o); o += 256 * 256 * 2;
    unsigned short* Wt3p = (unsigned short*)(ws + o); o += 48 * 256 * 2;

    int2* ebuf = (int2*)B1;   // lifetime: partition_edges..bucket_csr, before B1's first write

    const int EB    = NE / 1024;                  // 3125
    const int RGRID = (NN + 3) / 4;               // 25000
    const int GXM   = (NN + BM - 1) / BM;         // 782
    const int G3    = (NN + 63) / 64;             // 1563

    // binned CSR build
    hipMemsetAsync(gcount, 0, BN_BUCK * sizeof(int), stream);
    bucket_count<<<EB, 256, 0, stream>>>(ei + NE, gcount);
    bucket_scan<<<1, 256, 0, stream>>>(gcount, bucketBase, bucketFill, row_ptr);
    partition_edges<<<EB, 256, 0, stream>>>(ei, ev, bucketFill, ebuf);
    bucket_csr<<<BN_BUCK, 512, 0, stream>>>(bucketBase, ebuf, row_ptr, cp);

    // prep: weights + int8 x table
    prep_w<<<560, 256, 0, stream>>>(W1, W2, W3, Wt1, Wt2, Wt3p);
    quant_x<<<RGRID, 256, 0, stream>>>(x, Q8, Sc);

    // Layer 1: agg = A @ x (paired int8 gather) ; h1 = relu(agg @ W1)
    spmm_i8<0><<<RGRID, 256, 0, stream>>>(row_ptr, cp, Q8, Sc, B1);
    gemm_mfma<<<dim3(GXM, 2), 256, 0, stream>>>(B1, Wt1, B0, NN, 1);

    // Layer 2: quantize h1 (uint8), agg = A @ h1 ; h2 = relu(agg @ W2)
    quant_h<<<RGRID, 256, 0, stream>>>(B0, Q8, Sc);
    spmm_i8<1><<<RGRID, 256, 0, stream>>>(row_ptr, cp, Q8, Sc, B1);
    gemm_mfma<<<dim3(GXM, 2), 256, 0, stream>>>(B1, Wt2, B0, NN, 1);

    // Layer 3 (reordered): Lb = h2 @ W3, then fused spmm40 + log_softmax
    gemm3_mfma<<<G3, 256, 0, stream>>>(B0, Wt3p, Lb);
    spmm40_lsm<<<RGRID, 256, 0, stream>>>(row_ptr, cp, Lb, out);
}

// Round 16
// 610.055 us; speedup vs baseline: 3.4006x; 3.4006x over previous
//
#include <hip/hip_runtime.h>
#include <math.h>

#define NN 100000
#define NE 3200000
#define FD 256        // feature dim
#define NC 40         // classes
#define BN_BUCK 196   // ceil(NN / 512)

typedef unsigned int u32;
typedef __attribute__((ext_vector_type(8))) short short8;
typedef __attribute__((ext_vector_type(4))) float f32x4;

#define AS1 __attribute__((address_space(1)))
#define AS3 __attribute__((address_space(3)))

static __device__ __forceinline__ float bf2f(unsigned short h) {
    return __builtin_bit_cast(float, ((u32)h) << 16);
}
static __device__ __forceinline__ unsigned short f2bf(float f) {
    u32 u = __builtin_bit_cast(u32, f);
    u += 0x7fffu + ((u >> 16) & 1u);   // RNE
    return (unsigned short)(u >> 16);
}

// ---------------- binned CSR build ----------------

__global__ __launch_bounds__(256) void bucket_count(const int* __restrict__ ei_dst, int* __restrict__ gcount) {
    __shared__ int sh[BN_BUCK];
    int t = threadIdx.x;
    if (t < BN_BUCK) sh[t] = 0;
    __syncthreads();
    int i = blockIdx.x * 1024 + t * 4;
    int4 d = *reinterpret_cast<const int4*>(ei_dst + i);
    atomicAdd(&sh[d.x >> 9], 1);
    atomicAdd(&sh[d.y >> 9], 1);
    atomicAdd(&sh[d.z >> 9], 1);
    atomicAdd(&sh[d.w >> 9], 1);
    __syncthreads();
    if (t < BN_BUCK && sh[t]) atomicAdd(&gcount[t], sh[t]);
}

__global__ __launch_bounds__(256) void bucket_scan(const int* __restrict__ gcount,
                                                   int* __restrict__ bucketBase,
                                                   int* __restrict__ bucketFill,
                                                   int* __restrict__ row_ptr) {
    __shared__ int s[256];
    int t = threadIdx.x;
    int v = (t < BN_BUCK) ? gcount[t] : 0;
    s[t] = v;
    __syncthreads();
    for (int d = 1; d < 256; d <<= 1) {
        int x = (t >= d) ? s[t - d] : 0;
        __syncthreads();
        s[t] += x;
        __syncthreads();
    }
    int excl = s[t] - v;
    if (t < BN_BUCK) {
        bucketBase[t] = excl;
        bucketFill[t] = excl;
    }
    if (t == 0) {
        bucketBase[BN_BUCK] = NE;
        row_ptr[NN] = NE;
    }
}

__global__ __launch_bounds__(256) void partition_edges(const int* __restrict__ ei, const float* __restrict__ ev,
                                                       int* __restrict__ bucketFill, int2* __restrict__ ebuf) {
    __shared__ int cnt[BN_BUCK];
    __shared__ int gb[BN_BUCK];
    __shared__ int fill[BN_BUCK];
    int t = threadIdx.x;
    if (t < BN_BUCK) { cnt[t] = 0; fill[t] = 0; }
    __syncthreads();
    int i = blockIdx.x * 1024 + t * 4;
    int4 s4 = *reinterpret_cast<const int4*>(ei + i);
    int4 d4 = *reinterpret_cast<const int4*>(ei + NE + i);
    float4 v4 = *reinterpret_cast<const float4*>(ev + i);
    int b0 = d4.x >> 9, b1 = d4.y >> 9, b2 = d4.z >> 9, b3 = d4.w >> 9;
    atomicAdd(&cnt[b0], 1);
    atomicAdd(&cnt[b1], 1);
    atomicAdd(&cnt[b2], 1);
    atomicAdd(&cnt[b3], 1);
    __syncthreads();
    if (t < BN_BUCK && cnt[t]) gb[t] = atomicAdd(&bucketFill[t], cnt[t]);
    __syncthreads();
    int r;
    r = atomicAdd(&fill[b0], 1); ebuf[gb[b0] + r] = make_int2((s4.x << 9) | (d4.x & 511), __float_as_int(v4.x));
    r = atomicAdd(&fill[b1], 1); ebuf[gb[b1] + r] = make_int2((s4.y << 9) | (d4.y & 511), __float_as_int(v4.y));
    r = atomicAdd(&fill[b2], 1); ebuf[gb[b2] + r] = make_int2((s4.z << 9) | (d4.z & 511), __float_as_int(v4.z));
    r = atomicAdd(&fill[b3], 1); ebuf[gb[b3] + r] = make_int2((s4.w << 9) | (d4.w & 511), __float_as_int(v4.w));
}

// 512 threads: one thread per bucket-node; count -> 512-wide scan -> place
__global__ __launch_bounds__(512) void bucket_csr(const int* __restrict__ bucketBase,
                                                  const int2* __restrict__ ebuf,
                                                  int* __restrict__ row_ptr, int2* __restrict__ cp) {
    __shared__ int cnt[512];
    __shared__ int s[512];
    int b = blockIdx.x, t = threadIdx.x;
    int beg = bucketBase[b], end = bucketBase[b + 1];
    cnt[t] = 0;
    __syncthreads();
    for (int e = beg + t; e < end; e += 512)
        atomicAdd(&cnt[ebuf[e].x & 511], 1);
    __syncthreads();
    int c = cnt[t];
    s[t] = c;
    __syncthreads();
    for (int d = 1; d < 512; d <<= 1) {
        int x = (t >= d) ? s[t - d] : 0;
        __syncthreads();
        s[t] += x;
        __syncthreads();
    }
    int excl = s[t] - c;
    int g = b * 512 + t;
    if (g < NN) row_ptr[g] = beg + excl;
    __syncthreads();
    cnt[t] = excl;
    __syncthreads();
    for (int e = beg + t; e < end; e += 512) {
        int2 E = ebuf[e];
        int r = atomicAdd(&cnt[E.x & 511], 1);
        cp[beg + r] = make_int2(E.x >> 9, E.y);
    }
}

// ------- prep (merged): x -> signed int8 table + scales ; weights -> bf16 transposed -------

__global__ __launch_bounds__(256) void prep(const float* __restrict__ x,
                                            const float* __restrict__ W1,
                                            const float* __restrict__ W2,
                                            const float* __restrict__ W3,
                                            u32* __restrict__ Q, float* __restrict__ Sc,
                                            unsigned short* __restrict__ Wt1,
                                            unsigned short* __restrict__ Wt2,
                                            unsigned short* __restrict__ Wt3p) {
    int b = blockIdx.x, t = threadIdx.x;
    if (b < 25000) {
        int wv = t >> 6, l = t & 63;
        int row = b * 4 + wv;
        float4 v = reinterpret_cast<const float4*>(x)[(size_t)row * 64 + l];
        float m = fmaxf(fmaxf(fabsf(v.x), fabsf(v.y)), fmaxf(fabsf(v.z), fabsf(v.w)));
        for (int d = 32; d > 0; d >>= 1) m = fmaxf(m, __shfl_xor(m, d));
        float inv = (m > 0.f) ? 127.f / m : 0.f;
        int q0 = (int)rintf(v.x * inv), q1 = (int)rintf(v.y * inv);
        int q2 = (int)rintf(v.z * inv), q3 = (int)rintf(v.w * inv);
        u32 pk = (u32)(q0 & 255) | ((u32)(q1 & 255) << 8) | ((u32)(q2 & 255) << 16) | ((u32)(q3 & 255) << 24);
        Q[(size_t)row * 64 + l] = pk;
        if (l == 0) Sc[row] = m * (1.f / 127.f);
    } else if (b < 25256) {
        int n = b - 25000;
        Wt1[n * 256 + t] = f2bf(W1[t * 256 + n]);
    } else if (b < 25512) {
        int n = b - 25256;
        Wt2[n * 256 + t] = f2bf(W2[t * 256 + n]);
    } else {
        int n = b - 25512;
        Wt3p[n * 256 + t] = (n < NC) ? f2bf(W3[t * NC + n]) : (unsigned short)0;
    }
}

__global__ __launch_bounds__(256) void quant_h(const unsigned short* __restrict__ H,
                                               u32* __restrict__ Q, float* __restrict__ Sc) {
    int wv = threadIdx.x >> 6, l = threadIdx.x & 63;
    int row = blockIdx.x * 4 + wv;
    ushort4 hv = reinterpret_cast<const ushort4*>(H)[(size_t)row * 64 + l];
    float v0 = bf2f(hv.x), v1 = bf2f(hv.y), v2 = bf2f(hv.z), v3 = bf2f(hv.w);
    float m = fmaxf(fmaxf(v0, v1), fmaxf(v2, v3));
    for (int d = 32; d > 0; d >>= 1) m = fmaxf(m, __shfl_xor(m, d));
    float inv = (m > 0.f) ? 255.f / m : 0.f;
    int q0 = (int)rintf(v0 * inv), q1 = (int)rintf(v1 * inv);
    int q2 = (int)rintf(v2 * inv), q3 = (int)rintf(v3 * inv);
    u32 pk = (u32)(q0 & 255) | ((u32)(q1 & 255) << 8) | ((u32)(q2 & 255) << 16) | ((u32)(q3 & 255) << 24);
    Q[(size_t)row * 64 + l] = pk;
    if (l == 0) Sc[row] = m * (1.f / 255.f);
}

// ------- SPMM int8 (r14-proven): one wave per dst row, depth-16 main + 8 + 4 + 2 tails -------

template <int UNSIGNED>
__global__ __launch_bounds__(256) void spmm_i8(const int* __restrict__ rp,
                                               const int2* __restrict__ cp,
                                               const u32* __restrict__ Q,
                                               const float* __restrict__ Sc,
                                               unsigned short* __restrict__ O) {
    int wv = threadIdx.x >> 6;
    int l = threadIdx.x & 63;
    int row = blockIdx.x * 4 + wv;
    if (row >= NN) return;
    int beg = __builtin_amdgcn_readfirstlane(rp[row]);
    int end = __builtin_amdgcn_readfirstlane(rp[row + 1]);
    float a0 = 0.f, a1 = 0.f, a2 = 0.f, a3 = 0.f;

#define ACC_I8(W, VS)                                                            \
    {                                                                            \
        u32 w_ = (W);                                                            \
        float p0_, p1_, p2_, p3_;                                                \
        if (UNSIGNED) {                                                          \
            p0_ = (float)(w_ & 255u);        p1_ = (float)((w_ >> 8) & 255u);    \
            p2_ = (float)((w_ >> 16) & 255u); p3_ = (float)(w_ >> 24);           \
        } else {                                                                 \
            p0_ = (float)(int)(char)(w_);        p1_ = (float)(int)(char)(w_ >> 8);  \
            p2_ = (float)(int)(char)(w_ >> 16);  p3_ = (float)(int)(char)(w_ >> 24); \
        }                                                                        \
        a0 += (VS) * p0_; a1 += (VS) * p1_; a2 += (VS) * p2_; a3 += (VS) * p3_;  \
    }

    int e = beg;
    int efull = beg + ((end - beg) & ~15);
    if (e < efull) {
        int2 m[16];
        float vs[16];
#pragma unroll
        for (int j = 0; j < 16; ++j) m[j] = cp[e + j];
#pragma unroll
        for (int j = 0; j < 16; ++j) vs[j] = __int_as_float(m[j].y) * Sc[m[j].x];
        e += 16;
        for (; e < efull; e += 16) {
            u32 hv[16];
#pragma unroll
            for (int j = 0; j < 16; ++j) hv[j] = Q[(size_t)m[j].x * 64 + l];
            int2 mn[16];
            float vsn[16];
#pragma unroll
            for (int j = 0; j < 16; ++j) mn[j] = cp[e + j];
#pragma unroll
            for (int j = 0; j < 16; ++j) vsn[j] = __int_as_float(mn[j].y) * Sc[mn[j].x];
#pragma unroll
            for (int j = 0; j < 16; ++j) ACC_I8(hv[j], vs[j]);
#pragma unroll
            for (int j = 0; j < 16; ++j) { m[j] = mn[j]; vs[j] = vsn[j]; }
        }
        {
            u32 hv[16];
#pragma unroll
            for (int j = 0; j < 16; ++j) hv[j] = Q[(size_t)m[j].x * 64 + l];
#pragma unroll
            for (int j = 0; j < 16; ++j) ACC_I8(hv[j], vs[j]);
        }
    }
    if (end - e >= 8) {                       // depth-8 tail stage
        int2 m[8];
        float vs[8];
#pragma unroll
        for (int j = 0; j < 8; ++j) m[j] = cp[e + j];
#pragma unroll
        for (int j = 0; j < 8; ++j) vs[j] = __int_as_float(m[j].y) * Sc[m[j].x];
        u32 hv[8];
#pragma unroll
        for (int j = 0; j < 8; ++j) hv[j] = Q[(size_t)m[j].x * 64 + l];
#pragma unroll
        for (int j = 0; j < 8; ++j) ACC_I8(hv[j], vs[j]);
        e += 8;
    }
    if (end - e >= 4) {                       // depth-4 tail stage
        int2 m[4];
        float vs[4];
#pragma unroll
        for (int j = 0; j < 4; ++j) m[j] = cp[e + j];
#pragma unroll
        for (int j = 0; j < 4; ++j) vs[j] = __int_as_float(m[j].y) * Sc[m[j].x];
        u32 hv[4];
#pragma unroll
        for (int j = 0; j < 4; ++j) hv[j] = Q[(size_t)m[j].x * 64 + l];
#pragma unroll
        for (int j = 0; j < 4; ++j) ACC_I8(hv[j], vs[j]);
        e += 4;
    }
    if (end - e >= 2) {                       // depth-2 tail stage
        int2 m0 = cp[e];
        int2 m1 = cp[e + 1];
        float v0 = __int_as_float(m0.y) * Sc[m0.x];
        float v1 = __int_as_float(m1.y) * Sc[m1.x];
        u32 h0 = Q[(size_t)m0.x * 64 + l];
        u32 h1 = Q[(size_t)m1.x * 64 + l];
        ACC_I8(h0, v0);
        ACC_I8(h1, v1);
        e += 2;
    }
    for (; e < end; ++e) {
        int2 m1 = cp[e];
        float vs1 = __int_as_float(m1.y) * Sc[m1.x];
        u32 hv = Q[(size_t)m1.x * 64 + l];
        ACC_I8(hv, vs1);
    }
#undef ACC_I8
    ushort4 o;
    o.x = f2bf(a0); o.y = f2bf(a1); o.z = f2bf(a2); o.w = f2bf(a3);
    reinterpret_cast<ushort4*>(O)[(size_t)row * 64 + l] = o;
}

// ---------------- MFMA GEMM (r9-proven): BM=128, BN=128, relu, out bf16 ----------------

#define BM 128
#define BKK 64

__global__ __launch_bounds__(256) void gemm_mfma(const unsigned short* __restrict__ A,
                                                 const unsigned short* __restrict__ Wt,
                                                 unsigned short* __restrict__ C, int M, int relu) {
    __shared__ unsigned short As[BM * BKK];
    __shared__ unsigned short Bs[BM * BKK];
    int tid = threadIdx.x;
    int l = tid & 63;
    int w = tid >> 6;
    int wm = w >> 1, wn = w & 1;
    int bm = blockIdx.x * BM;
    int bn = blockIdx.y * BM;

    f32x4 acc[4][4] = {};

    for (int kt = 0; kt < 4; ++kt) {
        int k0 = kt * BKK;
#pragma unroll
        for (int i = 0; i < 4; ++i) {
            int e = i * 256 + tid;
            int row = e >> 3;
            int c = e & 7;
            int cs = c ^ (row & 7);
            int ga = min(bm + row, M - 1);
            __builtin_amdgcn_global_load_lds(
                (const AS1 u32*)(A + (size_t)ga * 256 + k0 + cs * 8),
                (AS3 u32*)(As + e * 8), 16, 0, 0);
            __builtin_amdgcn_global_load_lds(
                (const AS1 u32*)(Wt + (size_t)(bn + row) * 256 + k0 + cs * 8),
                (AS3 u32*)(Bs + e * 8), 16, 0, 0);
        }
        __syncthreads();
#pragma unroll
        for (int h = 0; h < 2; ++h) {
            short8 av[4], bv[4];
#pragma unroll
            for (int m = 0; m < 4; ++m) {
                int row = wm * 64 + m * 16 + (l & 15);
                int cs = (h * 4 + (l >> 4)) ^ (row & 7);
                av[m] = *(const short8*)(As + row * BKK + cs * 8);
            }
#pragma unroll
            for (int n = 0; n < 4; ++n) {
                int row = wn * 64 + n * 16 + (l & 15);
                int cs = (h * 4 + (l >> 4)) ^ (row & 7);
                bv[n] = *(const short8*)(Bs + row * BKK + cs * 8);
            }
#pragma unroll
            for (int m = 0; m < 4; ++m)
#pragma unroll
                for (int n = 0; n < 4; ++n)
                    acc[m][n] = __builtin_amdgcn_mfma_f32_16x16x32_bf16(av[m], bv[n], acc[m][n], 0, 0, 0);
        }
        __syncthreads();
    }

#pragma unroll
    for (int m = 0; m < 4; ++m)
#pragma unroll
        for (int r = 0; r < 4; ++r) {
            int gr = bm + wm * 64 + m * 16 + (l >> 4) * 4 + r;
            if (gr >= M) continue;
#pragma unroll
            for (int n = 0; n < 4; ++n) {
                int gc = bn + wn * 64 + n * 16 + (l & 15);
                float v = acc[m][n][r];
                if (relu) v = fmaxf(v, 0.f);
                C[(size_t)gr * 256 + gc] = f2bf(v);
            }
        }
}

// ------- GEMM3 (r9-proven): Lb[M,40](bf16) = H2[M,256](bf16) @ Wt3p[48][256](bf16) -------

__global__ __launch_bounds__(256) void gemm3_mfma(const unsigned short* __restrict__ H2,
                                                  const unsigned short* __restrict__ Wt3p,
                                                  unsigned short* __restrict__ Lb) {
    int tid = threadIdx.x, l = tid & 63, w = tid >> 6;
    int row0 = blockIdx.x * 64 + w * 16;
    f32x4 acc[3] = {};
    int ra = min(row0 + (l & 15), NN - 1);
    const unsigned short* ap = H2 + (size_t)ra * 256 + (l >> 4) * 8;
#pragma unroll
    for (int kt = 0; kt < 8; ++kt) {
        short8 av = *(const short8*)(ap + kt * 32);
#pragma unroll
        for (int j = 0; j < 3; ++j) {
            const unsigned short* bp = Wt3p + (size_t)(j * 16 + (l & 15)) * 256 + kt * 32 + (l >> 4) * 8;
            short8 bv = *(const short8*)bp;
            acc[j] = __builtin_amdgcn_mfma_f32_16x16x32_bf16(av, bv, acc[j], 0, 0, 0);
        }
    }
#pragma unroll
    for (int j = 0; j < 3; ++j)
#pragma unroll
        for (int r = 0; r < 4; ++r) {
            int gr = row0 + (l >> 4) * 4 + r;
            int gc = j * 16 + (l & 15);
            if (gr < NN && gc < NC) Lb[(size_t)gr * NC + gc] = f2bf(acc[j][r]);
        }
}

// ------- fused: out[row] = log_softmax( sum_e val * Lb[src] ), depth 16 + 8 + 4 tails -------

__global__ __launch_bounds__(256) void spmm40_lsm(const int* __restrict__ rp,
                                                  const int2* __restrict__ cp,
                                                  const unsigned short* __restrict__ Lb,
                                                  float* __restrict__ out) {
    int wv = threadIdx.x >> 6, l = threadIdx.x & 63;
    int row = blockIdx.x * 4 + wv;
    if (row >= NN) return;
    int beg = __builtin_amdgcn_readfirstlane(rp[row]);
    int end = __builtin_amdgcn_readfirstlane(rp[row + 1]);
    int lc = min(l, NC - 1);
    float acc = 0.f;
    int e = beg;
    int efull = beg + ((end - beg) & ~15);
    if (e < efull) {
        int2 m[16];
#pragma unroll
        for (int j = 0; j < 16; ++j) m[j] = cp[e + j];
        e += 16;
        for (; e < efull; e += 16) {
            unsigned short hv[16];
#pragma unroll
            for (int j = 0; j < 16; ++j) hv[j] = Lb[(size_t)m[j].x * NC + lc];
            int2 mn[16];
#pragma unroll
            for (int j = 0; j < 16; ++j) mn[j] = cp[e + j];
#pragma unroll
            for (int j = 0; j < 16; ++j)
                acc += __int_as_float(m[j].y) * bf2f(hv[j]);
#pragma unroll
            for (int j = 0; j < 16; ++j) m[j] = mn[j];
        }
        {
            unsigned short hv[16];
#pragma unroll
            for (int j = 0; j < 16; ++j) hv[j] = Lb[(size_t)m[j].x * NC + lc];
#pragma unroll
            for (int j = 0; j < 16; ++j)
                acc += __int_as_float(m[j].y) * bf2f(hv[j]);
        }
    }
    if (end - e >= 8) {
        int2 m[8];
#pragma unroll
        for (int j = 0; j < 8; ++j) m[j] = cp[e + j];
        unsigned short hv[8];
#pragma unroll
        for (int j = 0; j < 8; ++j) hv[j] = Lb[(size_t)m[j].x * NC + lc];
#pragma unroll
        for (int j = 0; j < 8; ++j)
            acc += __int_as_float(m[j].y) * bf2f(hv[j]);
        e += 8;
    }
    if (end - e >= 4) {
        int2 m[4];
#pragma unroll
        for (int j = 0; j < 4; ++j) m[j] = cp[e + j];
        unsigned short hv[4];
#pragma unroll
        for (int j = 0; j < 4; ++j) hv[j] = Lb[(size_t)m[j].x * NC + lc];
#pragma unroll
        for (int j = 0; j < 4; ++j)
            acc += __int_as_float(m[j].y) * bf2f(hv[j]);
        e += 4;
    }
    if (end - e >= 2) {
        int2 m0 = cp[e];
        int2 m1 = cp[e + 1];
        unsigned short h0 = Lb[(size_t)m0.x * NC + lc];
        unsigned short h1 = Lb[(size_t)m1.x * NC + lc];
        acc += __int_as_float(m0.y) * bf2f(h0);
        acc += __int_as_float(m1.y) * bf2f(h1);
        e += 2;
    }
    for (; e < end; ++e) {
        int2 m1 = cp[e];
        acc += __int_as_float(m1.y) * bf2f(Lb[(size_t)m1.x * NC + lc]);
    }
    float v = (l < NC) ? acc : -INFINITY;
    float mx = v;
    for (int d = 32; d > 0; d >>= 1) mx = fmaxf(mx, __shfl_xor(mx, d));
    float ex = (l < NC) ? expf(v - mx) : 0.f;
    float ssum = ex;
    for (int d = 32; d > 0; d >>= 1) ssum += __shfl_xor(ssum, d);
    float ls = logf(ssum);
    if (l < NC) out[(size_t)row * NC + l] = v - mx - ls;
}

// ---------------- launch ----------------

extern "C" void kernel_launch(void* const* d_in, const int* in_sizes, int n_in,
                              void* d_out, int out_size, void* d_ws, size_t ws_size,
                              hipStream_t stream) {
    const float* x  = (const float*)d_in[0];
    const int*   ei = (const int*)d_in[1];
    const float* ev = (const float*)d_in[2];
    const float* W1 = (const float*)d_in[3];
    const float* W2 = (const float*)d_in[4];
    const float* W3 = (const float*)d_in[5];
    float* out = (float*)d_out;

    char* ws = (char*)d_ws;
    size_t o = 0;
    unsigned short* B0 = (unsigned short*)(ws + o); o += (size_t)NN * FD * 2;   // 51.2 MB (h1/h2)
    unsigned short* B1 = (unsigned short*)(ws + o); o += (size_t)NN * FD * 2;   // 51.2 MB agg (aliases ebuf)
    u32*   Q8          = (u32*)(ws + o);            o += (size_t)NN * FD;       // 25.6 MB int8 table
    float* Sc          = (float*)(ws + o);          o += (size_t)NN * 4;        // 400 KB scales
    unsigned short* Lb = (unsigned short*)(ws + o); o += (size_t)NN * NC * 2;   // 8 MB
    int2*  cp          = (int2*)(ws + o);           o += (size_t)NE * 8;        // 25.6 MB
    int*   row_ptr     = (int*)(ws + o);            o += 400128;
    int*   gcount      = (int*)(ws + o);            o += 1024;
    int*   bucketBase  = (int*)(ws + o);            o += 1024;
    int*   bucketFill  = (int*)(ws + o);            o += 1024;
    unsigned short* Wt1  = (unsigned short*)(ws + o); o += 256 * 256 * 2;
    unsigned short* Wt2  = (unsigned short*)(ws + o); o += 256 * 256 * 2;
    unsigned short* Wt3p = (unsigned short*)(ws + o); o += 48 * 256 * 2;

    int2* ebuf = (int2*)B1;   // lifetime: partition_edges..bucket_csr, before B1's first write

    const int EB    = NE / 1024;                  // 3125
    const int RGRID = (NN + 3) / 4;               // 25000
    const int GXM   = (NN + BM - 1) / BM;         // 782
    const int G3    = (NN + 63) / 64;             // 1563

    // binned CSR build
    hipMemsetAsync(gcount, 0, BN_BUCK * sizeof(int), stream);
    bucket_count<<<EB, 256, 0, stream>>>(ei + NE, gcount);
    bucket_scan<<<1, 256, 0, stream>>>(gcount, bucketBase, bucketFill, row_ptr);
    partition_edges<<<EB, 256, 0, stream>>>(ei, ev, bucketFill, ebuf);
    bucket_csr<<<BN_BUCK, 512, 0, stream>>>(bucketBase, ebuf, row_ptr, cp);

    // prep (merged): x -> int8 + scales, weights transposed bf16
    prep<<<25560, 256, 0, stream>>>(x, W1, W2, W3, Q8, Sc, Wt1, Wt2, Wt3p);

    // Layer 1: agg = A @ x (int8 gather) ; h1 = relu(agg @ W1)
    spmm_i8<0><<<RGRID, 256, 0, stream>>>(row_ptr, cp, Q8, Sc, B1);
    gemm_mfma<<<dim3(GXM, 2), 256, 0, stream>>>(B1, Wt1, B0, NN, 1);

    // Layer 2: quantize h1 (uint8), agg = A @ h1 ; h2 = relu(agg @ W2)
    quant_h<<<RGRID, 256, 0, stream>>>(B0, Q8, Sc);
    spmm_i8<1><<<RGRID, 256, 0, stream>>>(row_ptr, cp, Q8, Sc, B1);
    gemm_mfma<<<dim3(GXM, 2), 256, 0, stream>>>(B1, Wt2, B0, NN, 1);

    // Layer 3 (reordered): Lb = h2 @ W3, then fused spmm40 + log_softmax
    gemm3_mfma<<<G3, 256, 0, stream>>>(B0, Wt3p, Lb);
    spmm40_lsm<<<RGRID, 256, 0, stream>>>(row_ptr, cp, Lb, out);
}

// Round 17
// 598.896 us; speedup vs baseline: 3.4640x; 1.0186x over previous
//
#include <hip/hip_runtime.h>
#include <math.h>

#define NN 100000
#define NE 3200000
#define FD 256        // feature dim
#define NC 40         // classes
#define BN_BUCK 196   // ceil(NN / 512)

typedef unsigned int u32;
typedef __attribute__((ext_vector_type(8))) short short8;
typedef __attribute__((ext_vector_type(4))) float f32x4;

#define AS1 __attribute__((address_space(1)))
#define AS3 __attribute__((address_space(3)))

static __device__ __forceinline__ float bf2f(unsigned short h) {
    return __builtin_bit_cast(float, ((u32)h) << 16);
}
static __device__ __forceinline__ unsigned short f2bf(float f) {
    u32 u = __builtin_bit_cast(u32, f);
    u += 0x7fffu + ((u >> 16) & 1u);   // RNE
    return (unsigned short)(u >> 16);
}

// ---------------- binned CSR build ----------------

__global__ __launch_bounds__(256) void bucket_count(const int* __restrict__ ei_dst, int* __restrict__ gcount) {
    __shared__ int sh[BN_BUCK];
    int t = threadIdx.x;
    if (t < BN_BUCK) sh[t] = 0;
    __syncthreads();
    int i = blockIdx.x * 1024 + t * 4;
    int4 d = *reinterpret_cast<const int4*>(ei_dst + i);
    atomicAdd(&sh[d.x >> 9], 1);
    atomicAdd(&sh[d.y >> 9], 1);
    atomicAdd(&sh[d.z >> 9], 1);
    atomicAdd(&sh[d.w >> 9], 1);
    __syncthreads();
    if (t < BN_BUCK && sh[t]) atomicAdd(&gcount[t], sh[t]);
}

__global__ __launch_bounds__(256) void bucket_scan(const int* __restrict__ gcount,
                                                   int* __restrict__ bucketBase,
                                                   int* __restrict__ bucketFill,
                                                   int* __restrict__ row_ptr) {
    __shared__ int s[256];
    int t = threadIdx.x;
    int v = (t < BN_BUCK) ? gcount[t] : 0;
    s[t] = v;
    __syncthreads();
    for (int d = 1; d < 256; d <<= 1) {
        int x = (t >= d) ? s[t - d] : 0;
        __syncthreads();
        s[t] += x;
        __syncthreads();
    }
    int excl = s[t] - v;
    if (t < BN_BUCK) {
        bucketBase[t] = excl;
        bucketFill[t] = excl;
    }
    if (t == 0) {
        bucketBase[BN_BUCK] = NE;
        row_ptr[NN] = NE;
    }
}

__global__ __launch_bounds__(256) void partition_edges(const int* __restrict__ ei, const float* __restrict__ ev,
                                                       int* __restrict__ bucketFill, int2* __restrict__ ebuf) {
    __shared__ int cnt[BN_BUCK];
    __shared__ int gb[BN_BUCK];
    __shared__ int fill[BN_BUCK];
    int t = threadIdx.x;
    if (t < BN_BUCK) { cnt[t] = 0; fill[t] = 0; }
    __syncthreads();
    int i = blockIdx.x * 1024 + t * 4;
    int4 s4 = *reinterpret_cast<const int4*>(ei + i);
    int4 d4 = *reinterpret_cast<const int4*>(ei + NE + i);
    float4 v4 = *reinterpret_cast<const float4*>(ev + i);
    int b0 = d4.x >> 9, b1 = d4.y >> 9, b2 = d4.z >> 9, b3 = d4.w >> 9;
    atomicAdd(&cnt[b0], 1);
    atomicAdd(&cnt[b1], 1);
    atomicAdd(&cnt[b2], 1);
    atomicAdd(&cnt[b3], 1);
    __syncthreads();
    if (t < BN_BUCK && cnt[t]) gb[t] = atomicAdd(&bucketFill[t], cnt[t]);
    __syncthreads();
    int r;
    r = atomicAdd(&fill[b0], 1); ebuf[gb[b0] + r] = make_int2((s4.x << 9) | (d4.x & 511), __float_as_int(v4.x));
    r = atomicAdd(&fill[b1], 1); ebuf[gb[b1] + r] = make_int2((s4.y << 9) | (d4.y & 511), __float_as_int(v4.y));
    r = atomicAdd(&fill[b2], 1); ebuf[gb[b2] + r] = make_int2((s4.z << 9) | (d4.z & 511), __float_as_int(v4.z));
    r = atomicAdd(&fill[b3], 1); ebuf[gb[b3] + r] = make_int2((s4.w << 9) | (d4.w & 511), __float_as_int(v4.w));
}

// 512 threads: one thread per bucket-node; count -> 512-wide scan -> place
__global__ __launch_bounds__(512) void bucket_csr(const int* __restrict__ bucketBase,
                                                  const int2* __restrict__ ebuf,
                                                  int* __restrict__ row_ptr, int2* __restrict__ cp) {
    __shared__ int cnt[512];
    __shared__ int s[512];
    int b = blockIdx.x, t = threadIdx.x;
    int beg = bucketBase[b], end = bucketBase[b + 1];
    cnt[t] = 0;
    __syncthreads();
    for (int e = beg + t; e < end; e += 512)
        atomicAdd(&cnt[ebuf[e].x & 511], 1);
    __syncthreads();
    int c = cnt[t];
    s[t] = c;
    __syncthreads();
    for (int d = 1; d < 512; d <<= 1) {
        int x = (t >= d) ? s[t - d] : 0;
        __syncthreads();
        s[t] += x;
        __syncthreads();
    }
    int excl = s[t] - c;
    int g = b * 512 + t;
    if (g < NN) row_ptr[g] = beg + excl;
    __syncthreads();
    cnt[t] = excl;
    __syncthreads();
    for (int e = beg + t; e < end; e += 512) {
        int2 E = ebuf[e];
        int r = atomicAdd(&cnt[E.x & 511], 1);
        cp[beg + r] = make_int2(E.x >> 9, E.y);
    }
}

// ------- prep (merged): x -> signed int8 table + scales ; weights -> bf16 transposed -------

__global__ __launch_bounds__(256) void prep(const float* __restrict__ x,
                                            const float* __restrict__ W1,
                                            const float* __restrict__ W2,
                                            const float* __restrict__ W3,
                                            u32* __restrict__ Q, float* __restrict__ Sc,
                                            unsigned short* __restrict__ Wt1,
                                            unsigned short* __restrict__ Wt2,
                                            unsigned short* __restrict__ Wt3p) {
    int b = blockIdx.x, t = threadIdx.x;
    if (b < 25000) {
        int wv = t >> 6, l = t & 63;
        int row = b * 4 + wv;
        float4 v = reinterpret_cast<const float4*>(x)[(size_t)row * 64 + l];
        float m = fmaxf(fmaxf(fabsf(v.x), fabsf(v.y)), fmaxf(fabsf(v.z), fabsf(v.w)));
        for (int d = 32; d > 0; d >>= 1) m = fmaxf(m, __shfl_xor(m, d));
        float inv = (m > 0.f) ? 127.f / m : 0.f;
        int q0 = (int)rintf(v.x * inv), q1 = (int)rintf(v.y * inv);
        int q2 = (int)rintf(v.z * inv), q3 = (int)rintf(v.w * inv);
        u32 pk = (u32)(q0 & 255) | ((u32)(q1 & 255) << 8) | ((u32)(q2 & 255) << 16) | ((u32)(q3 & 255) << 24);
        Q[(size_t)row * 64 + l] = pk;
        if (l == 0) Sc[row] = m * (1.f / 127.f);
    } else if (b < 25256) {
        int n = b - 25000;
        Wt1[n * 256 + t] = f2bf(W1[t * 256 + n]);
    } else if (b < 25512) {
        int n = b - 25256;
        Wt2[n * 256 + t] = f2bf(W2[t * 256 + n]);
    } else {
        int n = b - 25512;
        Wt3p[n * 256 + t] = (n < NC) ? f2bf(W3[t * NC + n]) : (unsigned short)0;
    }
}

// ------- SPMM int8 (r14-proven): one wave per dst row, depth-16 main + 8 + 4 + 2 tails -------

template <int UNSIGNED>
__global__ __launch_bounds__(256) void spmm_i8(const int* __restrict__ rp,
                                               const int2* __restrict__ cp,
                                               const u32* __restrict__ Q,
                                               const float* __restrict__ Sc,
                                               unsigned short* __restrict__ O) {
    int wv = threadIdx.x >> 6;
    int l = threadIdx.x & 63;
    int row = blockIdx.x * 4 + wv;
    if (row >= NN) return;
    int beg = __builtin_amdgcn_readfirstlane(rp[row]);
    int end = __builtin_amdgcn_readfirstlane(rp[row + 1]);
    float a0 = 0.f, a1 = 0.f, a2 = 0.f, a3 = 0.f;

#define ACC_I8(W, VS)                                                            \
    {                                                                            \
        u32 w_ = (W);                                                            \
        float p0_, p1_, p2_, p3_;                                                \
        if (UNSIGNED) {                                                          \
            p0_ = (float)(w_ & 255u);        p1_ = (float)((w_ >> 8) & 255u);    \
            p2_ = (float)((w_ >> 16) & 255u); p3_ = (float)(w_ >> 24);           \
        } else {                                                                 \
            p0_ = (float)(int)(char)(w_);        p1_ = (float)(int)(char)(w_ >> 8);  \
            p2_ = (float)(int)(char)(w_ >> 16);  p3_ = (float)(int)(char)(w_ >> 24); \
        }                                                                        \
        a0 += (VS) * p0_; a1 += (VS) * p1_; a2 += (VS) * p2_; a3 += (VS) * p3_;  \
    }

    int e = beg;
    int efull = beg + ((end - beg) & ~15);
    if (e < efull) {
        int2 m[16];
        float vs[16];
#pragma unroll
        for (int j = 0; j < 16; ++j) m[j] = cp[e + j];
#pragma unroll
        for (int j = 0; j < 16; ++j) vs[j] = __int_as_float(m[j].y) * Sc[m[j].x];
        e += 16;
        for (; e < efull; e += 16) {
            u32 hv[16];
#pragma unroll
            for (int j = 0; j < 16; ++j) hv[j] = Q[(size_t)m[j].x * 64 + l];
            int2 mn[16];
            float vsn[16];
#pragma unroll
            for (int j = 0; j < 16; ++j) mn[j] = cp[e + j];
#pragma unroll
            for (int j = 0; j < 16; ++j) vsn[j] = __int_as_float(mn[j].y) * Sc[mn[j].x];
#pragma unroll
            for (int j = 0; j < 16; ++j) ACC_I8(hv[j], vs[j]);
#pragma unroll
            for (int j = 0; j < 16; ++j) { m[j] = mn[j]; vs[j] = vsn[j]; }
        }
        {
            u32 hv[16];
#pragma unroll
            for (int j = 0; j < 16; ++j) hv[j] = Q[(size_t)m[j].x * 64 + l];
#pragma unroll
            for (int j = 0; j < 16; ++j) ACC_I8(hv[j], vs[j]);
        }
    }
    if (end - e >= 8) {
        int2 m[8];
        float vs[8];
#pragma unroll
        for (int j = 0; j < 8; ++j) m[j] = cp[e + j];
#pragma unroll
        for (int j = 0; j < 8; ++j) vs[j] = __int_as_float(m[j].y) * Sc[m[j].x];
        u32 hv[8];
#pragma unroll
        for (int j = 0; j < 8; ++j) hv[j] = Q[(size_t)m[j].x * 64 + l];
#pragma unroll
        for (int j = 0; j < 8; ++j) ACC_I8(hv[j], vs[j]);
        e += 8;
    }
    if (end - e >= 4) {
        int2 m[4];
        float vs[4];
#pragma unroll
        for (int j = 0; j < 4; ++j) m[j] = cp[e + j];
#pragma unroll
        for (int j = 0; j < 4; ++j) vs[j] = __int_as_float(m[j].y) * Sc[m[j].x];
        u32 hv[4];
#pragma unroll
        for (int j = 0; j < 4; ++j) hv[j] = Q[(size_t)m[j].x * 64 + l];
#pragma unroll
        for (int j = 0; j < 4; ++j) ACC_I8(hv[j], vs[j]);
        e += 4;
    }
    if (end - e >= 2) {
        int2 m0 = cp[e];
        int2 m1 = cp[e + 1];
        float v0 = __int_as_float(m0.y) * Sc[m0.x];
        float v1 = __int_as_float(m1.y) * Sc[m1.x];
        u32 h0 = Q[(size_t)m0.x * 64 + l];
        u32 h1 = Q[(size_t)m1.x * 64 + l];
        ACC_I8(h0, v0);
        ACC_I8(h1, v1);
        e += 2;
    }
    for (; e < end; ++e) {
        int2 m1 = cp[e];
        float vs1 = __int_as_float(m1.y) * Sc[m1.x];
        u32 hv = Q[(size_t)m1.x * 64 + l];
        ACC_I8(hv, vs1);
    }
#undef ACC_I8
    ushort4 o;
    o.x = f2bf(a0); o.y = f2bf(a1); o.z = f2bf(a2); o.w = f2bf(a3);
    reinterpret_cast<ushort4*>(O)[(size_t)row * 64 + l] = o;
}

#define BM 128
#define BKK 64

// ------- GEMM1+QUANT fused: Q8/Sc = uint8-quant( relu( A[M,256] @ Wt1 ) ); h1 never materialized.
//         One block owns complete 256-wide rows (bn-half loop, same 32KB staging LDS). -------

__global__ __launch_bounds__(256) void gemm1_quant(const unsigned short* __restrict__ A,
                                                   const unsigned short* __restrict__ Wt,
                                                   unsigned char* __restrict__ Q8b,
                                                   float* __restrict__ Sc, int M) {
    __shared__ unsigned short As[BM * BKK];
    __shared__ unsigned short Bs[BM * BKK];
    __shared__ unsigned rmax[BM];
    int tid = threadIdx.x;
    int l = tid & 63;
    int w = tid >> 6;
    int wm = w >> 1, wn = w & 1;
    int bm = blockIdx.x * BM;
    if (tid < BM) rmax[tid] = 0u;

    f32x4 acc[4][4];
    u32 p0[4][4][2];   // half0 packed bf16 (relu'd); [m][n][r-pair], all static-indexed

    for (int bh = 0; bh < 2; ++bh) {
        int bn = bh * 128;
#pragma unroll
        for (int m = 0; m < 4; ++m)
#pragma unroll
            for (int n = 0; n < 4; ++n)
                acc[m][n] = (f32x4){0.f, 0.f, 0.f, 0.f};

        for (int kt = 0; kt < 4; ++kt) {
            int k0 = kt * BKK;
#pragma unroll
            for (int i = 0; i < 4; ++i) {
                int e = i * 256 + tid;
                int row = e >> 3;
                int c = e & 7;
                int cs = c ^ (row & 7);
                int ga = min(bm + row, M - 1);
                __builtin_amdgcn_global_load_lds(
                    (const AS1 u32*)(A + (size_t)ga * 256 + k0 + cs * 8),
                    (AS3 u32*)(As + e * 8), 16, 0, 0);
                __builtin_amdgcn_global_load_lds(
                    (const AS1 u32*)(Wt + (size_t)(bn + row) * 256 + k0 + cs * 8),
                    (AS3 u32*)(Bs + e * 8), 16, 0, 0);
            }
            __syncthreads();
#pragma unroll
            for (int h = 0; h < 2; ++h) {
                short8 av[4], bv[4];
#pragma unroll
                for (int m = 0; m < 4; ++m) {
                    int row = wm * 64 + m * 16 + (l & 15);
                    int cs = (h * 4 + (l >> 4)) ^ (row & 7);
                    av[m] = *(const short8*)(As + row * BKK + cs * 8);
                }
#pragma unroll
                for (int n = 0; n < 4; ++n) {
                    int row = wn * 64 + n * 16 + (l & 15);
                    int cs = (h * 4 + (l >> 4)) ^ (row & 7);
                    bv[n] = *(const short8*)(Bs + row * BKK + cs * 8);
                }
#pragma unroll
                for (int m = 0; m < 4; ++m)
#pragma unroll
                    for (int n = 0; n < 4; ++n)
                        acc[m][n] = __builtin_amdgcn_mfma_f32_16x16x32_bf16(av[m], bv[n], acc[m][n], 0, 0, 0);
            }
            __syncthreads();
        }
        if (bh == 0) {
#pragma unroll
            for (int m = 0; m < 4; ++m)
#pragma unroll
                for (int n = 0; n < 4; ++n) {
                    float v0 = fmaxf(acc[m][n][0], 0.f);
                    float v1 = fmaxf(acc[m][n][1], 0.f);
                    float v2 = fmaxf(acc[m][n][2], 0.f);
                    float v3 = fmaxf(acc[m][n][3], 0.f);
                    p0[m][n][0] = (u32)f2bf(v0) | ((u32)f2bf(v1) << 16);
                    p0[m][n][1] = (u32)f2bf(v2) | ((u32)f2bf(v3) << 16);
                }
        }
    }

    // per-(m,r) row max over this thread's 8 cols, then across the 16-lane col group
    float mx[4][4];   // [m][r], static-indexed
#pragma unroll
    for (int m = 0; m < 4; ++m)
#pragma unroll
        for (int r = 0; r < 4; ++r) {
            float v = 0.f;
#pragma unroll
            for (int n = 0; n < 4; ++n) {
                v = fmaxf(v, fmaxf(acc[m][n][r], 0.f));
                u32 pw = p0[m][n][r >> 1];
                unsigned short b = (r & 1) ? (unsigned short)(pw >> 16) : (unsigned short)(pw & 0xffff);
                v = fmaxf(v, bf2f(b));
            }
            v = fmaxf(v, __shfl_xor(v, 1));
            v = fmaxf(v, __shfl_xor(v, 2));
            v = fmaxf(v, __shfl_xor(v, 4));
            v = fmaxf(v, __shfl_xor(v, 8));
            mx[m][r] = v;
        }
    if ((l & 15) == 0) {
#pragma unroll
        for (int m = 0; m < 4; ++m)
#pragma unroll
            for (int r = 0; r < 4; ++r)
                atomicMax(&rmax[wm * 64 + m * 16 + (l >> 4) * 4 + r], __float_as_uint(mx[m][r]));
    }
    __syncthreads();

    // quantize & store bytes (uint8, scale rm/255) + Sc
#pragma unroll
    for (int m = 0; m < 4; ++m)
#pragma unroll
        for (int r = 0; r < 4; ++r) {
            int lr = wm * 64 + m * 16 + (l >> 4) * 4 + r;
            int gr = bm + lr;
            float rm = __uint_as_float(rmax[lr]);
            float inv = (rm > 0.f) ? 255.f / rm : 0.f;
            if (gr < M) {
#pragma unroll
                for (int n = 0; n < 4; ++n) {
                    u32 pw = p0[m][n][r >> 1];
                    unsigned short b = (r & 1) ? (unsigned short)(pw >> 16) : (unsigned short)(pw & 0xffff);
                    int q0v = (int)rintf(bf2f(b) * inv);
                    int q1v = (int)rintf(fmaxf(acc[m][n][r], 0.f) * inv);
                    Q8b[(size_t)gr * 256 + wn * 64 + n * 16 + (l & 15)] = (unsigned char)q0v;
                    Q8b[(size_t)gr * 256 + 128 + wn * 64 + n * 16 + (l & 15)] = (unsigned char)q1v;
                }
                if (wn == 0 && (l & 15) == 0) Sc[gr] = rm * (1.f / 255.f);
            }
        }
}

// ---------------- MFMA GEMM (r9-proven): BM=128, BN=128, relu, out bf16 ----------------

__global__ __launch_bounds__(256) void gemm_mfma(const unsigned short* __restrict__ A,
                                                 const unsigned short* __restrict__ Wt,
                                                 unsigned short* __restrict__ C, int M, int relu) {
    __shared__ unsigned short As[BM * BKK];
    __shared__ unsigned short Bs[BM * BKK];
    int tid = threadIdx.x;
    int l = tid & 63;
    int w = tid >> 6;
    int wm = w >> 1, wn = w & 1;
    int bm = blockIdx.x * BM;
    int bn = blockIdx.y * BM;

    f32x4 acc[4][4] = {};

    for (int kt = 0; kt < 4; ++kt) {
        int k0 = kt * BKK;
#pragma unroll
        for (int i = 0; i < 4; ++i) {
            int e = i * 256 + tid;
            int row = e >> 3;
            int c = e & 7;
            int cs = c ^ (row & 7);
            int ga = min(bm + row, M - 1);
            __builtin_amdgcn_global_load_lds(
                (const AS1 u32*)(A + (size_t)ga * 256 + k0 + cs * 8),
                (AS3 u32*)(As + e * 8), 16, 0, 0);
            __builtin_amdgcn_global_load_lds(
                (const AS1 u32*)(Wt + (size_t)(bn + row) * 256 + k0 + cs * 8),
                (AS3 u32*)(Bs + e * 8), 16, 0, 0);
        }
        __syncthreads();
#pragma unroll
        for (int h = 0; h < 2; ++h) {
            short8 av[4], bv[4];
#pragma unroll
            for (int m = 0; m < 4; ++m) {
                int row = wm * 64 + m * 16 + (l & 15);
                int cs = (h * 4 + (l >> 4)) ^ (row & 7);
                av[m] = *(const short8*)(As + row * BKK + cs * 8);
            }
#pragma unroll
            for (int n = 0; n < 4; ++n) {
                int row = wn * 64 + n * 16 + (l & 15);
                int cs = (h * 4 + (l >> 4)) ^ (row & 7);
                bv[n] = *(const short8*)(Bs + row * BKK + cs * 8);
            }
#pragma unroll
            for (int m = 0; m < 4; ++m)
#pragma unroll
                for (int n = 0; n < 4; ++n)
                    acc[m][n] = __builtin_amdgcn_mfma_f32_16x16x32_bf16(av[m], bv[n], acc[m][n], 0, 0, 0);
        }
        __syncthreads();
    }

#pragma unroll
    for (int m = 0; m < 4; ++m)
#pragma unroll
        for (int r = 0; r < 4; ++r) {
            int gr = bm + wm * 64 + m * 16 + (l >> 4) * 4 + r;
            if (gr >= M) continue;
#pragma unroll
            for (int n = 0; n < 4; ++n) {
                int gc = bn + wn * 64 + n * 16 + (l & 15);
                float v = acc[m][n][r];
                if (relu) v = fmaxf(v, 0.f);
                C[(size_t)gr * 256 + gc] = f2bf(v);
            }
        }
}

// ------- GEMM3 (r9-proven): Lb[M,40](bf16) = H2[M,256](bf16) @ Wt3p[48][256](bf16) -------

__global__ __launch_bounds__(256) void gemm3_mfma(const unsigned short* __restrict__ H2,
                                                  const unsigned short* __restrict__ Wt3p,
                                                  unsigned short* __restrict__ Lb) {
    int tid = threadIdx.x, l = tid & 63, w = tid >> 6;
    int row0 = blockIdx.x * 64 + w * 16;
    f32x4 acc[3] = {};
    int ra = min(row0 + (l & 15), NN - 1);
    const unsigned short* ap = H2 + (size_t)ra * 256 + (l >> 4) * 8;
#pragma unroll
    for (int kt = 0; kt < 8; ++kt) {
        short8 av = *(const short8*)(ap + kt * 32);
#pragma unroll
        for (int j = 0; j < 3; ++j) {
            const unsigned short* bp = Wt3p + (size_t)(j * 16 + (l & 15)) * 256 + kt * 32 + (l >> 4) * 8;
            short8 bv = *(const short8*)bp;
            acc[j] = __builtin_amdgcn_mfma_f32_16x16x32_bf16(av, bv, acc[j], 0, 0, 0);
        }
    }
#pragma unroll
    for (int j = 0; j < 3; ++j)
#pragma unroll
        for (int r = 0; r < 4; ++r) {
            int gr = row0 + (l >> 4) * 4 + r;
            int gc = j * 16 + (l & 15);
            if (gr < NN && gc < NC) Lb[(size_t)gr * NC + gc] = f2bf(acc[j][r]);
        }
}

// ------- fused: out[row] = log_softmax( sum_e val * Lb[src] ), depth 16 + 8 + 4 + 2 tails -------

__global__ __launch_bounds__(256) void spmm40_lsm(const int* __restrict__ rp,
                                                  const int2* __restrict__ cp,
                                                  const unsigned short* __restrict__ Lb,
                                                  float* __restrict__ out) {
    int wv = threadIdx.x >> 6, l = threadIdx.x & 63;
    int row = blockIdx.x * 4 + wv;
    if (row >= NN) return;
    int beg = __builtin_amdgcn_readfirstlane(rp[row]);
    int end = __builtin_amdgcn_readfirstlane(rp[row + 1]);
    int lc = min(l, NC - 1);
    float acc = 0.f;
    int e = beg;
    int efull = beg + ((end - beg) & ~15);
    if (e < efull) {
        int2 m[16];
#pragma unroll
        for (int j = 0; j < 16; ++j) m[j] = cp[e + j];
        e += 16;
        for (; e < efull; e += 16) {
            unsigned short hv[16];
#pragma unroll
            for (int j = 0; j < 16; ++j) hv[j] = Lb[(size_t)m[j].x * NC + lc];
            int2 mn[16];
#pragma unroll
            for (int j = 0; j < 16; ++j) mn[j] = cp[e + j];
#pragma unroll
            for (int j = 0; j < 16; ++j)
                acc += __int_as_float(m[j].y) * bf2f(hv[j]);
#pragma unroll
            for (int j = 0; j < 16; ++j) m[j] = mn[j];
        }
        {
            unsigned short hv[16];
#pragma unroll
            for (int j = 0; j < 16; ++j) hv[j] = Lb[(size_t)m[j].x * NC + lc];
#pragma unroll
            for (int j = 0; j < 16; ++j)
                acc += __int_as_float(m[j].y) * bf2f(hv[j]);
        }
    }
    if (end - e >= 8) {
        int2 m[8];
#pragma unroll
        for (int j = 0; j < 8; ++j) m[j] = cp[e + j];
        unsigned short hv[8];
#pragma unroll
        for (int j = 0; j < 8; ++j) hv[j] = Lb[(size_t)m[j].x * NC + lc];
#pragma unroll
        for (int j = 0; j < 8; ++j)
            acc += __int_as_float(m[j].y) * bf2f(hv[j]);
        e += 8;
    }
    if (end - e >= 4) {
        int2 m[4];
#pragma unroll
        for (int j = 0; j < 4; ++j) m[j] = cp[e + j];
        unsigned short hv[4];
#pragma unroll
        for (int j = 0; j < 4; ++j) hv[j] = Lb[(size_t)m[j].x * NC + lc];
#pragma unroll
        for (int j = 0; j < 4; ++j)
            acc += __int_as_float(m[j].y) * bf2f(hv[j]);
        e += 4;
    }
    if (end - e >= 2) {
        int2 m0 = cp[e];
        int2 m1 = cp[e + 1];
        unsigned short h0 = Lb[(size_t)m0.x * NC + lc];
        unsigned short h1 = Lb[(size_t)m1.x * NC + lc];
        acc += __int_as_float(m0.y) * bf2f(h0);
        acc += __int_as_float(m1.y) * bf2f(h1);
        e += 2;
    }
    for (; e < end; ++e) {
        int2 m1 = cp[e];
        acc += __int_as_float(m1.y) * bf2f(Lb[(size_t)m1.x * NC + lc]);
    }
    float v = (l < NC) ? acc : -INFINITY;
    float mx = v;
    for (int d = 32; d > 0; d >>= 1) mx = fmaxf(mx, __shfl_xor(mx, d));
    float ex = (l < NC) ? expf(v - mx) : 0.f;
    float ssum = ex;
    for (int d = 32; d > 0; d >>= 1) ssum += __shfl_xor(ssum, d);
    float ls = logf(ssum);
    if (l < NC) out[(size_t)row * NC + l] = v - mx - ls;
}

// ---------------- launch ----------------

extern "C" void kernel_launch(void* const* d_in, const int* in_sizes, int n_in,
                              void* d_out, int out_size, void* d_ws, size_t ws_size,
                              hipStream_t stream) {
    const float* x  = (const float*)d_in[0];
    const int*   ei = (const int*)d_in[1];
    const float* ev = (const float*)d_in[2];
    const float* W1 = (const float*)d_in[3];
    const float* W2 = (const float*)d_in[4];
    const float* W3 = (const float*)d_in[5];
    float* out = (float*)d_out;

    char* ws = (char*)d_ws;
    size_t o = 0;
    unsigned short* B0 = (unsigned short*)(ws + o); o += (size_t)NN * FD * 2;   // 51.2 MB (h2)
    unsigned short* B1 = (unsigned short*)(ws + o); o += (size_t)NN * FD * 2;   // 51.2 MB agg (aliases ebuf)
    u32*   Q8          = (u32*)(ws + o);            o += (size_t)NN * FD;       // 25.6 MB int8 table
    float* Sc          = (float*)(ws + o);          o += (size_t)NN * 4;        // 400 KB scales
    unsigned short* Lb = (unsigned short*)(ws + o); o += (size_t)NN * NC * 2;   // 8 MB
    int2*  cp          = (int2*)(ws + o);           o += (size_t)NE * 8;        // 25.6 MB
    int*   row_ptr     = (int*)(ws + o);            o += 400128;
    int*   gcount      = (int*)(ws + o);            o += 1024;
    int*   bucketBase  = (int*)(ws + o);            o += 1024;
    int*   bucketFill  = (int*)(ws + o);            o += 1024;
    unsigned short* Wt1  = (unsigned short*)(ws + o); o += 256 * 256 * 2;
    unsigned short* Wt2  = (unsigned short*)(ws + o); o += 256 * 256 * 2;
    unsigned short* Wt3p = (unsigned short*)(ws + o); o += 48 * 256 * 2;

    int2* ebuf = (int2*)B1;   // lifetime: partition_edges..bucket_csr, before B1's first write

    const int EB    = NE / 1024;                  // 3125
    const int RGRID = (NN + 3) / 4;               // 25000
    const int GXM   = (NN + BM - 1) / BM;         // 782
    const int G3    = (NN + 63) / 64;             // 1563

    // binned CSR build
    hipMemsetAsync(gcount, 0, BN_BUCK * sizeof(int), stream);
    bucket_count<<<EB, 256, 0, stream>>>(ei + NE, gcount);
    bucket_scan<<<1, 256, 0, stream>>>(gcount, bucketBase, bucketFill, row_ptr);
    partition_edges<<<EB, 256, 0, stream>>>(ei, ev, bucketFill, ebuf);
    bucket_csr<<<BN_BUCK, 512, 0, stream>>>(bucketBase, ebuf, row_ptr, cp);

    // prep (merged): x -> int8 + scales, weights transposed bf16
    prep<<<25560, 256, 0, stream>>>(x, W1, W2, W3, Q8, Sc, Wt1, Wt2, Wt3p);

    // Layer 1: agg = A @ x (int8 gather) ; Q8/Sc = uint8-quant(relu(agg @ W1)) fused (h1 skipped)
    spmm_i8<0><<<RGRID, 256, 0, stream>>>(row_ptr, cp, Q8, Sc, B1);
    gemm1_quant<<<GXM, 256, 0, stream>>>(B1, Wt1, (unsigned char*)Q8, Sc, NN);

    // Layer 2: agg = A @ h1 (uint8 gather) ; h2 = relu(agg @ W2)
    spmm_i8<1><<<RGRID, 256, 0, stream>>>(row_ptr, cp, Q8, Sc, B1);
    gemm_mfma<<<dim3(GXM, 2), 256, 0, stream>>>(B1, Wt2, B0, NN, 1);

    // Layer 3 (reordered): Lb = h2 @ W3, then fused spmm40 + log_softmax
    gemm3_mfma<<<G3, 256, 0, stream>>>(B0, Wt3p, Lb);
    spmm40_lsm<<<RGRID, 256, 0, stream>>>(row_ptr, cp, Lb, out);
}

// Round 18
// 598.018 us; speedup vs baseline: 3.4691x; 1.0015x over previous
//
#include <hip/hip_runtime.h>
#include <math.h>

#define NN 100000
#define NE 3200000
#define FD 256        // feature dim
#define NC 40         // classes
#define BN_BUCK 196   // ceil(NN / 512)

typedef unsigned int u32;
typedef __attribute__((ext_vector_type(8))) short short8;
typedef __attribute__((ext_vector_type(4))) float f32x4;

#define AS1 __attribute__((address_space(1)))
#define AS3 __attribute__((address_space(3)))

static __device__ __forceinline__ float bf2f(unsigned short h) {
    return __builtin_bit_cast(float, ((u32)h) << 16);
}
static __device__ __forceinline__ unsigned short f2bf(float f) {
    u32 u = __builtin_bit_cast(u32, f);
    u += 0x7fffu + ((u >> 16) & 1u);   // RNE
    return (unsigned short)(u >> 16);
}

// ---------------- binned CSR build ----------------

__global__ __launch_bounds__(256) void bucket_count(const int* __restrict__ ei_dst, int* __restrict__ gcount) {
    __shared__ int sh[BN_BUCK];
    int t = threadIdx.x;
    if (t < BN_BUCK) sh[t] = 0;
    __syncthreads();
    int i = blockIdx.x * 1024 + t * 4;
    int4 d = *reinterpret_cast<const int4*>(ei_dst + i);
    atomicAdd(&sh[d.x >> 9], 1);
    atomicAdd(&sh[d.y >> 9], 1);
    atomicAdd(&sh[d.z >> 9], 1);
    atomicAdd(&sh[d.w >> 9], 1);
    __syncthreads();
    if (t < BN_BUCK && sh[t]) atomicAdd(&gcount[t], sh[t]);
}

__global__ __launch_bounds__(256) void bucket_scan(const int* __restrict__ gcount,
                                                   int* __restrict__ bucketBase,
                                                   int* __restrict__ bucketFill,
                                                   int* __restrict__ row_ptr) {
    __shared__ int s[256];
    int t = threadIdx.x;
    int v = (t < BN_BUCK) ? gcount[t] : 0;
    s[t] = v;
    __syncthreads();
    for (int d = 1; d < 256; d <<= 1) {
        int x = (t >= d) ? s[t - d] : 0;
        __syncthreads();
        s[t] += x;
        __syncthreads();
    }
    int excl = s[t] - v;
    if (t < BN_BUCK) {
        bucketBase[t] = excl;
        bucketFill[t] = excl;
    }
    if (t == 0) {
        bucketBase[BN_BUCK] = NE;
        row_ptr[NN] = NE;
    }
}

__global__ __launch_bounds__(256) void partition_edges(const int* __restrict__ ei, const float* __restrict__ ev,
                                                       int* __restrict__ bucketFill, int2* __restrict__ ebuf) {
    __shared__ int cnt[BN_BUCK];
    __shared__ int gb[BN_BUCK];
    __shared__ int fill[BN_BUCK];
    int t = threadIdx.x;
    if (t < BN_BUCK) { cnt[t] = 0; fill[t] = 0; }
    __syncthreads();
    int i = blockIdx.x * 1024 + t * 4;
    int4 s4 = *reinterpret_cast<const int4*>(ei + i);
    int4 d4 = *reinterpret_cast<const int4*>(ei + NE + i);
    float4 v4 = *reinterpret_cast<const float4*>(ev + i);
    int b0 = d4.x >> 9, b1 = d4.y >> 9, b2 = d4.z >> 9, b3 = d4.w >> 9;
    atomicAdd(&cnt[b0], 1);
    atomicAdd(&cnt[b1], 1);
    atomicAdd(&cnt[b2], 1);
    atomicAdd(&cnt[b3], 1);
    __syncthreads();
    if (t < BN_BUCK && cnt[t]) gb[t] = atomicAdd(&bucketFill[t], cnt[t]);
    __syncthreads();
    int r;
    r = atomicAdd(&fill[b0], 1); ebuf[gb[b0] + r] = make_int2((s4.x << 9) | (d4.x & 511), __float_as_int(v4.x));
    r = atomicAdd(&fill[b1], 1); ebuf[gb[b1] + r] = make_int2((s4.y << 9) | (d4.y & 511), __float_as_int(v4.y));
    r = atomicAdd(&fill[b2], 1); ebuf[gb[b2] + r] = make_int2((s4.z << 9) | (d4.z & 511), __float_as_int(v4.z));
    r = atomicAdd(&fill[b3], 1); ebuf[gb[b3] + r] = make_int2((s4.w << 9) | (d4.w & 511), __float_as_int(v4.w));
}

// 512 threads: one thread per bucket-node; count -> 512-wide scan -> place
__global__ __launch_bounds__(512) void bucket_csr(const int* __restrict__ bucketBase,
                                                  const int2* __restrict__ ebuf,
                                                  int* __restrict__ row_ptr, int2* __restrict__ cp) {
    __shared__ int cnt[512];
    __shared__ int s[512];
    int b = blockIdx.x, t = threadIdx.x;
    int beg = bucketBase[b], end = bucketBase[b + 1];
    cnt[t] = 0;
    __syncthreads();
    for (int e = beg + t; e < end; e += 512)
        atomicAdd(&cnt[ebuf[e].x & 511], 1);
    __syncthreads();
    int c = cnt[t];
    s[t] = c;
    __syncthreads();
    for (int d = 1; d < 512; d <<= 1) {
        int x = (t >= d) ? s[t - d] : 0;
        __syncthreads();
        s[t] += x;
        __syncthreads();
    }
    int excl = s[t] - c;
    int g = b * 512 + t;
    if (g < NN) row_ptr[g] = beg + excl;
    __syncthreads();
    cnt[t] = excl;
    __syncthreads();
    for (int e = beg + t; e < end; e += 512) {
        int2 E = ebuf[e];
        int r = atomicAdd(&cnt[E.x & 511], 1);
        cp[beg + r] = make_int2(E.x >> 9, E.y);
    }
}

// ------- prep (merged): x -> signed int8 table + scales ; weights -> bf16 transposed -------

__global__ __launch_bounds__(256) void prep(const float* __restrict__ x,
                                            const float* __restrict__ W1,
                                            const float* __restrict__ W2,
                                            const float* __restrict__ W3,
                                            u32* __restrict__ Q, float* __restrict__ Sc,
                                            unsigned short* __restrict__ Wt1,
                                            unsigned short* __restrict__ Wt2,
                                            unsigned short* __restrict__ Wt3p) {
    int b = blockIdx.x, t = threadIdx.x;
    if (b < 25000) {
        int wv = t >> 6, l = t & 63;
        int row = b * 4 + wv;
        float4 v = reinterpret_cast<const float4*>(x)[(size_t)row * 64 + l];
        float m = fmaxf(fmaxf(fabsf(v.x), fabsf(v.y)), fmaxf(fabsf(v.z), fabsf(v.w)));
        for (int d = 32; d > 0; d >>= 1) m = fmaxf(m, __shfl_xor(m, d));
        float inv = (m > 0.f) ? 127.f / m : 0.f;
        int q0 = (int)rintf(v.x * inv), q1 = (int)rintf(v.y * inv);
        int q2 = (int)rintf(v.z * inv), q3 = (int)rintf(v.w * inv);
        u32 pk = (u32)(q0 & 255) | ((u32)(q1 & 255) << 8) | ((u32)(q2 & 255) << 16) | ((u32)(q3 & 255) << 24);
        Q[(size_t)row * 64 + l] = pk;
        if (l == 0) Sc[row] = m * (1.f / 127.f);
    } else if (b < 25256) {
        int n = b - 25000;
        Wt1[n * 256 + t] = f2bf(W1[t * 256 + n]);
    } else if (b < 25512) {
        int n = b - 25256;
        Wt2[n * 256 + t] = f2bf(W2[t * 256 + n]);
    } else {
        int n = b - 25512;
        Wt3p[n * 256 + t] = (n < NC) ? f2bf(W3[t * NC + n]) : (unsigned short)0;
    }
}

// ------- SPMM int8 (r14-proven): one wave per dst row, depth-16 main + 8 + 4 + 2 tails -------

template <int UNSIGNED>
__global__ __launch_bounds__(256) void spmm_i8(const int* __restrict__ rp,
                                               const int2* __restrict__ cp,
                                               const u32* __restrict__ Q,
                                               const float* __restrict__ Sc,
                                               unsigned short* __restrict__ O) {
    int wv = threadIdx.x >> 6;
    int l = threadIdx.x & 63;
    int row = blockIdx.x * 4 + wv;
    if (row >= NN) return;
    int beg = __builtin_amdgcn_readfirstlane(rp[row]);
    int end = __builtin_amdgcn_readfirstlane(rp[row + 1]);
    float a0 = 0.f, a1 = 0.f, a2 = 0.f, a3 = 0.f;

#define ACC_I8(W, VS)                                                            \
    {                                                                            \
        u32 w_ = (W);                                                            \
        float p0_, p1_, p2_, p3_;                                                \
        if (UNSIGNED) {                                                          \
            p0_ = (float)(w_ & 255u);        p1_ = (float)((w_ >> 8) & 255u);    \
            p2_ = (float)((w_ >> 16) & 255u); p3_ = (float)(w_ >> 24);           \
        } else {                                                                 \
            p0_ = (float)(int)(char)(w_);        p1_ = (float)(int)(char)(w_ >> 8);  \
            p2_ = (float)(int)(char)(w_ >> 16);  p3_ = (float)(int)(char)(w_ >> 24); \
        }                                                                        \
        a0 += (VS) * p0_; a1 += (VS) * p1_; a2 += (VS) * p2_; a3 += (VS) * p3_;  \
    }

    int e = beg;
    int efull = beg + ((end - beg) & ~15);
    if (e < efull) {
        int2 m[16];
        float vs[16];
#pragma unroll
        for (int j = 0; j < 16; ++j) m[j] = cp[e + j];
#pragma unroll
        for (int j = 0; j < 16; ++j) vs[j] = __int_as_float(m[j].y) * Sc[m[j].x];
        e += 16;
        for (; e < efull; e += 16) {
            u32 hv[16];
#pragma unroll
            for (int j = 0; j < 16; ++j) hv[j] = Q[(size_t)m[j].x * 64 + l];
            int2 mn[16];
            float vsn[16];
#pragma unroll
            for (int j = 0; j < 16; ++j) mn[j] = cp[e + j];
#pragma unroll
            for (int j = 0; j < 16; ++j) vsn[j] = __int_as_float(mn[j].y) * Sc[mn[j].x];
#pragma unroll
            for (int j = 0; j < 16; ++j) ACC_I8(hv[j], vs[j]);
#pragma unroll
            for (int j = 0; j < 16; ++j) { m[j] = mn[j]; vs[j] = vsn[j]; }
        }
        {
            u32 hv[16];
#pragma unroll
            for (int j = 0; j < 16; ++j) hv[j] = Q[(size_t)m[j].x * 64 + l];
#pragma unroll
            for (int j = 0; j < 16; ++j) ACC_I8(hv[j], vs[j]);
        }
    }
    if (end - e >= 8) {
        int2 m[8];
        float vs[8];
#pragma unroll
        for (int j = 0; j < 8; ++j) m[j] = cp[e + j];
#pragma unroll
        for (int j = 0; j < 8; ++j) vs[j] = __int_as_float(m[j].y) * Sc[m[j].x];
        u32 hv[8];
#pragma unroll
        for (int j = 0; j < 8; ++j) hv[j] = Q[(size_t)m[j].x * 64 + l];
#pragma unroll
        for (int j = 0; j < 8; ++j) ACC_I8(hv[j], vs[j]);
        e += 8;
    }
    if (end - e >= 4) {
        int2 m[4];
        float vs[4];
#pragma unroll
        for (int j = 0; j < 4; ++j) m[j] = cp[e + j];
#pragma unroll
        for (int j = 0; j < 4; ++j) vs[j] = __int_as_float(m[j].y) * Sc[m[j].x];
        u32 hv[4];
#pragma unroll
        for (int j = 0; j < 4; ++j) hv[j] = Q[(size_t)m[j].x * 64 + l];
#pragma unroll
        for (int j = 0; j < 4; ++j) ACC_I8(hv[j], vs[j]);
        e += 4;
    }
    if (end - e >= 2) {
        int2 m0 = cp[e];
        int2 m1 = cp[e + 1];
        float v0 = __int_as_float(m0.y) * Sc[m0.x];
        float v1 = __int_as_float(m1.y) * Sc[m1.x];
        u32 h0 = Q[(size_t)m0.x * 64 + l];
        u32 h1 = Q[(size_t)m1.x * 64 + l];
        ACC_I8(h0, v0);
        ACC_I8(h1, v1);
        e += 2;
    }
    for (; e < end; ++e) {
        int2 m1 = cp[e];
        float vs1 = __int_as_float(m1.y) * Sc[m1.x];
        u32 hv = Q[(size_t)m1.x * 64 + l];
        ACC_I8(hv, vs1);
    }
#undef ACC_I8
    ushort4 o;
    o.x = f2bf(a0); o.y = f2bf(a1); o.z = f2bf(a2); o.w = f2bf(a3);
    reinterpret_cast<ushort4*>(O)[(size_t)row * 64 + l] = o;
}

#define BM 128
#define BKK 64

// ------- GEMM1+QUANT fused (r17-proven): Q8/Sc = uint8-quant( relu( A @ Wt1 ) ) -------

__global__ __launch_bounds__(256) void gemm1_quant(const unsigned short* __restrict__ A,
                                                   const unsigned short* __restrict__ Wt,
                                                   unsigned char* __restrict__ Q8b,
                                                   float* __restrict__ Sc, int M) {
    __shared__ unsigned short As[BM * BKK];
    __shared__ unsigned short Bs[BM * BKK];
    __shared__ unsigned rmax[BM];
    int tid = threadIdx.x;
    int l = tid & 63;
    int w = tid >> 6;
    int wm = w >> 1, wn = w & 1;
    int bm = blockIdx.x * BM;
    if (tid < BM) rmax[tid] = 0u;

    f32x4 acc[4][4];
    u32 p0[4][4][2];

    for (int bh = 0; bh < 2; ++bh) {
        int bn = bh * 128;
#pragma unroll
        for (int m = 0; m < 4; ++m)
#pragma unroll
            for (int n = 0; n < 4; ++n)
                acc[m][n] = (f32x4){0.f, 0.f, 0.f, 0.f};

        for (int kt = 0; kt < 4; ++kt) {
            int k0 = kt * BKK;
#pragma unroll
            for (int i = 0; i < 4; ++i) {
                int e = i * 256 + tid;
                int row = e >> 3;
                int c = e & 7;
                int cs = c ^ (row & 7);
                int ga = min(bm + row, M - 1);
                __builtin_amdgcn_global_load_lds(
                    (const AS1 u32*)(A + (size_t)ga * 256 + k0 + cs * 8),
                    (AS3 u32*)(As + e * 8), 16, 0, 0);
                __builtin_amdgcn_global_load_lds(
                    (const AS1 u32*)(Wt + (size_t)(bn + row) * 256 + k0 + cs * 8),
                    (AS3 u32*)(Bs + e * 8), 16, 0, 0);
            }
            __syncthreads();
#pragma unroll
            for (int h = 0; h < 2; ++h) {
                short8 av[4], bv[4];
#pragma unroll
                for (int m = 0; m < 4; ++m) {
                    int row = wm * 64 + m * 16 + (l & 15);
                    int cs = (h * 4 + (l >> 4)) ^ (row & 7);
                    av[m] = *(const short8*)(As + row * BKK + cs * 8);
                }
#pragma unroll
                for (int n = 0; n < 4; ++n) {
                    int row = wn * 64 + n * 16 + (l & 15);
                    int cs = (h * 4 + (l >> 4)) ^ (row & 7);
                    bv[n] = *(const short8*)(Bs + row * BKK + cs * 8);
                }
#pragma unroll
                for (int m = 0; m < 4; ++m)
#pragma unroll
                    for (int n = 0; n < 4; ++n)
                        acc[m][n] = __builtin_amdgcn_mfma_f32_16x16x32_bf16(av[m], bv[n], acc[m][n], 0, 0, 0);
            }
            __syncthreads();
        }
        if (bh == 0) {
#pragma unroll
            for (int m = 0; m < 4; ++m)
#pragma unroll
                for (int n = 0; n < 4; ++n) {
                    float v0 = fmaxf(acc[m][n][0], 0.f);
                    float v1 = fmaxf(acc[m][n][1], 0.f);
                    float v2 = fmaxf(acc[m][n][2], 0.f);
                    float v3 = fmaxf(acc[m][n][3], 0.f);
                    p0[m][n][0] = (u32)f2bf(v0) | ((u32)f2bf(v1) << 16);
                    p0[m][n][1] = (u32)f2bf(v2) | ((u32)f2bf(v3) << 16);
                }
        }
    }

    float mx[4][4];
#pragma unroll
    for (int m = 0; m < 4; ++m)
#pragma unroll
        for (int r = 0; r < 4; ++r) {
            float v = 0.f;
#pragma unroll
            for (int n = 0; n < 4; ++n) {
                v = fmaxf(v, fmaxf(acc[m][n][r], 0.f));
                u32 pw = p0[m][n][r >> 1];
                unsigned short b = (r & 1) ? (unsigned short)(pw >> 16) : (unsigned short)(pw & 0xffff);
                v = fmaxf(v, bf2f(b));
            }
            v = fmaxf(v, __shfl_xor(v, 1));
            v = fmaxf(v, __shfl_xor(v, 2));
            v = fmaxf(v, __shfl_xor(v, 4));
            v = fmaxf(v, __shfl_xor(v, 8));
            mx[m][r] = v;
        }
    if ((l & 15) == 0) {
#pragma unroll
        for (int m = 0; m < 4; ++m)
#pragma unroll
            for (int r = 0; r < 4; ++r)
                atomicMax(&rmax[wm * 64 + m * 16 + (l >> 4) * 4 + r], __float_as_uint(mx[m][r]));
    }
    __syncthreads();

#pragma unroll
    for (int m = 0; m < 4; ++m)
#pragma unroll
        for (int r = 0; r < 4; ++r) {
            int lr = wm * 64 + m * 16 + (l >> 4) * 4 + r;
            int gr = bm + lr;
            float rm = __uint_as_float(rmax[lr]);
            float inv = (rm > 0.f) ? 255.f / rm : 0.f;
            if (gr < M) {
#pragma unroll
                for (int n = 0; n < 4; ++n) {
                    u32 pw = p0[m][n][r >> 1];
                    unsigned short b = (r & 1) ? (unsigned short)(pw >> 16) : (unsigned short)(pw & 0xffff);
                    int q0v = (int)rintf(bf2f(b) * inv);
                    int q1v = (int)rintf(fmaxf(acc[m][n][r], 0.f) * inv);
                    Q8b[(size_t)gr * 256 + wn * 64 + n * 16 + (l & 15)] = (unsigned char)q0v;
                    Q8b[(size_t)gr * 256 + 128 + wn * 64 + n * 16 + (l & 15)] = (unsigned char)q1v;
                }
                if (wn == 0 && (l & 15) == 0) Sc[gr] = rm * (1.f / 255.f);
            }
        }
}

// ------- GEMM2+GEMM3 fused: Lb[M,40] = ( relu( A @ Wt2 ) ) @ W3 ; h2 lives only in LDS -------
// Per bn-half: MFMA h2 half-tile, park relu'd bf16 in As(wm=0 rows)/Bs(wm=1 rows) with the
// standard XOR swizzle, then MFMA that 128-col K-half against Wt3p, accumulating acc2.

__global__ __launch_bounds__(256) void gemm23(const unsigned short* __restrict__ A,
                                              const unsigned short* __restrict__ Wt2,
                                              const unsigned short* __restrict__ Wt3p,
                                              unsigned short* __restrict__ Lb, int M) {
    __shared__ unsigned short As[BM * BKK];   // doubles as h2 rows 0-63  [64][128]
    __shared__ unsigned short Bs[BM * BKK];   // doubles as h2 rows 64-127
    int tid = threadIdx.x;
    int l = tid & 63;
    int w = tid >> 6;
    int wm = w >> 1, wn = w & 1;
    int bm = blockIdx.x * BM;

    f32x4 acc[4][4];
    f32x4 acc2[2][3] = {};   // gemm3: rows w*32 + mm*16, cols j3*16

    for (int bh = 0; bh < 2; ++bh) {
        int bn = bh * 128;
#pragma unroll
        for (int m = 0; m < 4; ++m)
#pragma unroll
            for (int n = 0; n < 4; ++n)
                acc[m][n] = (f32x4){0.f, 0.f, 0.f, 0.f};

        for (int kt = 0; kt < 4; ++kt) {
            int k0 = kt * BKK;
#pragma unroll
            for (int i = 0; i < 4; ++i) {
                int e = i * 256 + tid;
                int row = e >> 3;
                int c = e & 7;
                int cs = c ^ (row & 7);
                int ga = min(bm + row, M - 1);
                __builtin_amdgcn_global_load_lds(
                    (const AS1 u32*)(A + (size_t)ga * 256 + k0 + cs * 8),
                    (AS3 u32*)(As + e * 8), 16, 0, 0);
                __builtin_amdgcn_global_load_lds(
                    (const AS1 u32*)(Wt2 + (size_t)(bn + row) * 256 + k0 + cs * 8),
                    (AS3 u32*)(Bs + e * 8), 16, 0, 0);
            }
            __syncthreads();
#pragma unroll
            for (int h = 0; h < 2; ++h) {
                short8 av[4], bv[4];
#pragma unroll
                for (int m = 0; m < 4; ++m) {
                    int row = wm * 64 + m * 16 + (l & 15);
                    int cs = (h * 4 + (l >> 4)) ^ (row & 7);
                    av[m] = *(const short8*)(As + row * BKK + cs * 8);
                }
#pragma unroll
                for (int n = 0; n < 4; ++n) {
                    int row = wn * 64 + n * 16 + (l & 15);
                    int cs = (h * 4 + (l >> 4)) ^ (row & 7);
                    bv[n] = *(const short8*)(Bs + row * BKK + cs * 8);
                }
#pragma unroll
                for (int m = 0; m < 4; ++m)
#pragma unroll
                    for (int n = 0; n < 4; ++n)
                        acc[m][n] = __builtin_amdgcn_mfma_f32_16x16x32_bf16(av[m], bv[n], acc[m][n], 0, 0, 0);
            }
            __syncthreads();
        }

        // park relu'd h2 half tile in LDS: h2[row][c] with row = wm*64 + m*16 + (l>>4)*4 + r,
        // c = wn*64 + n*16 + (l&15); chunk swizzle ^ (row&7). wm=0 -> As, wm=1 -> Bs.
        {
            unsigned short* H2s = (wm == 0) ? As : Bs;   // local rows 0..63
#pragma unroll
            for (int m = 0; m < 4; ++m)
#pragma unroll
                for (int r = 0; r < 4; ++r) {
                    int lr = m * 16 + (l >> 4) * 4 + r;          // 0..63
#pragma unroll
                    for (int n = 0; n < 4; ++n) {
                        int c = wn * 64 + n * 16 + (l & 15);     // 0..127
                        int cs = (c >> 3) ^ (lr & 7);
                        H2s[lr * 128 + cs * 8 + (c & 7)] = f2bf(fmaxf(acc[m][n][r], 0.f));
                    }
                }
        }
        __syncthreads();

        // gemm3 partial over k in [bh*128, bh*128+128): rows = w*32 + mm*16 + (l&15)
        {
            const unsigned short* H2s = (w < 2) ? As : Bs;
            int lrow = (w & 1) * 32;                             // local row base within the 64-row half
#pragma unroll
            for (int mm = 0; mm < 2; ++mm) {
                int lr = lrow + mm * 16 + (l & 15);              // 0..63 local row
#pragma unroll
                for (int kc = 0; kc < 4; ++kc) {
                    int cs = (kc * 4 + (l >> 4)) ^ (lr & 7);
                    short8 av = *(const short8*)(H2s + lr * 128 + cs * 8);
#pragma unroll
                    for (int j3 = 0; j3 < 3; ++j3) {
                        const unsigned short* bp = Wt3p + (size_t)(j3 * 16 + (l & 15)) * 256 + bh * 128 + kc * 32 + (l >> 4) * 8;
                        short8 bv = *(const short8*)bp;
                        acc2[mm][j3] = __builtin_amdgcn_mfma_f32_16x16x32_bf16(av, bv, acc2[mm][j3], 0, 0, 0);
                    }
                }
            }
        }
        __syncthreads();
    }

    // write Lb: rows w*32 + mm*16 + (l>>4)*4 + r, cols j3*16 + (l&15)
#pragma unroll
    for (int mm = 0; mm < 2; ++mm)
#pragma unroll
        for (int j3 = 0; j3 < 3; ++j3)
#pragma unroll
            for (int r = 0; r < 4; ++r) {
                int gr = bm + w * 32 + mm * 16 + (l >> 4) * 4 + r;
                int gc = j3 * 16 + (l & 15);
                if (gr < M && gc < NC) Lb[(size_t)gr * NC + gc] = f2bf(acc2[mm][j3][r]);
            }
}

// ------- fused: out[row] = log_softmax( sum_e val * Lb[src] ), depth 16 + 8 + 4 + 2 tails -------

__global__ __launch_bounds__(256) void spmm40_lsm(const int* __restrict__ rp,
                                                  const int2* __restrict__ cp,
                                                  const unsigned short* __restrict__ Lb,
                                                  float* __restrict__ out) {
    int wv = threadIdx.x >> 6, l = threadIdx.x & 63;
    int row = blockIdx.x * 4 + wv;
    if (row >= NN) return;
    int beg = __builtin_amdgcn_readfirstlane(rp[row]);
    int end = __builtin_amdgcn_readfirstlane(rp[row + 1]);
    int lc = min(l, NC - 1);
    float acc = 0.f;
    int e = beg;
    int efull = beg + ((end - beg) & ~15);
    if (e < efull) {
        int2 m[16];
#pragma unroll
        for (int j = 0; j < 16; ++j) m[j] = cp[e + j];
        e += 16;
        for (; e < efull; e += 16) {
            unsigned short hv[16];
#pragma unroll
            for (int j = 0; j < 16; ++j) hv[j] = Lb[(size_t)m[j].x * NC + lc];
            int2 mn[16];
#pragma unroll
            for (int j = 0; j < 16; ++j) mn[j] = cp[e + j];
#pragma unroll
            for (int j = 0; j < 16; ++j)
                acc += __int_as_float(m[j].y) * bf2f(hv[j]);
#pragma unroll
            for (int j = 0; j < 16; ++j) m[j] = mn[j];
        }
        {
            unsigned short hv[16];
#pragma unroll
            for (int j = 0; j < 16; ++j) hv[j] = Lb[(size_t)m[j].x * NC + lc];
#pragma unroll
            for (int j = 0; j < 16; ++j)
                acc += __int_as_float(m[j].y) * bf2f(hv[j]);
        }
    }
    if (end - e >= 8) {
        int2 m[8];
#pragma unroll
        for (int j = 0; j < 8; ++j) m[j] = cp[e + j];
        unsigned short hv[8];
#pragma unroll
        for (int j = 0; j < 8; ++j) hv[j] = Lb[(size_t)m[j].x * NC + lc];
#pragma unroll
        for (int j = 0; j < 8; ++j)
            acc += __int_as_float(m[j].y) * bf2f(hv[j]);
        e += 8;
    }
    if (end - e >= 4) {
        int2 m[4];
#pragma unroll
        for (int j = 0; j < 4; ++j) m[j] = cp[e + j];
        unsigned short hv[4];
#pragma unroll
        for (int j = 0; j < 4; ++j) hv[j] = Lb[(size_t)m[j].x * NC + lc];
#pragma unroll
        for (int j = 0; j < 4; ++j)
            acc += __int_as_float(m[j].y) * bf2f(hv[j]);
        e += 4;
    }
    if (end - e >= 2) {
        int2 m0 = cp[e];
        int2 m1 = cp[e + 1];
        unsigned short h0 = Lb[(size_t)m0.x * NC + lc];
        unsigned short h1 = Lb[(size_t)m1.x * NC + lc];
        acc += __int_as_float(m0.y) * bf2f(h0);
        acc += __int_as_float(m1.y) * bf2f(h1);
        e += 2;
    }
    for (; e < end; ++e) {
        int2 m1 = cp[e];
        acc += __int_as_float(m1.y) * bf2f(Lb[(size_t)m1.x * NC + lc]);
    }
    float v = (l < NC) ? acc : -INFINITY;
    float mx = v;
    for (int d = 32; d > 0; d >>= 1) mx = fmaxf(mx, __shfl_xor(mx, d));
    float ex = (l < NC) ? expf(v - mx) : 0.f;
    float ssum = ex;
    for (int d = 32; d > 0; d >>= 1) ssum += __shfl_xor(ssum, d);
    float ls = logf(ssum);
    if (l < NC) out[(size_t)row * NC + l] = v - mx - ls;
}

// ---------------- launch ----------------

extern "C" void kernel_launch(void* const* d_in, const int* in_sizes, int n_in,
                              void* d_out, int out_size, void* d_ws, size_t ws_size,
                              hipStream_t stream) {
    const float* x  = (const float*)d_in[0];
    const int*   ei = (const int*)d_in[1];
    const float* ev = (const float*)d_in[2];
    const float* W1 = (const float*)d_in[3];
    const float* W2 = (const float*)d_in[4];
    const float* W3 = (const float*)d_in[5];
    float* out = (float*)d_out;

    char* ws = (char*)d_ws;
    size_t o = 0;
    unsigned short* B1 = (unsigned short*)(ws + o); o += (size_t)NN * FD * 2;   // 51.2 MB agg (aliases ebuf)
    u32*   Q8          = (u32*)(ws + o);            o += (size_t)NN * FD;       // 25.6 MB int8 table
    float* Sc          = (float*)(ws + o);          o += (size_t)NN * 4;        // 400 KB scales
    unsigned short* Lb = (unsigned short*)(ws + o); o += (size_t)NN * NC * 2;   // 8 MB
    int2*  cp          = (int2*)(ws + o);           o += (size_t)NE * 8;        // 25.6 MB
    int*   row_ptr     = (int*)(ws + o);            o += 400128;
    int*   gcount      = (int*)(ws + o);            o += 1024;
    int*   bucketBase  = (int*)(ws + o);            o += 1024;
    int*   bucketFill  = (int*)(ws + o);            o += 1024;
    unsigned short* Wt1  = (unsigned short*)(ws + o); o += 256 * 256 * 2;
    unsigned short* Wt2  = (unsigned short*)(ws + o); o += 256 * 256 * 2;
    unsigned short* Wt3p = (unsigned short*)(ws + o); o += 48 * 256 * 2;

    int2* ebuf = (int2*)B1;   // lifetime: partition_edges..bucket_csr, before B1's first write

    const int EB    = NE / 1024;                  // 3125
    const int RGRID = (NN + 3) / 4;               // 25000
    const int GXM   = (NN + BM - 1) / BM;         // 782

    // binned CSR build
    hipMemsetAsync(gcount, 0, BN_BUCK * sizeof(int), stream);
    bucket_count<<<EB, 256, 0, stream>>>(ei + NE, gcount);
    bucket_scan<<<1, 256, 0, stream>>>(gcount, bucketBase, bucketFill, row_ptr);
    partition_edges<<<EB, 256, 0, stream>>>(ei, ev, bucketFill, ebuf);
    bucket_csr<<<BN_BUCK, 512, 0, stream>>>(bucketBase, ebuf, row_ptr, cp);

    // prep (merged): x -> int8 + scales, weights transposed bf16
    prep<<<25560, 256, 0, stream>>>(x, W1, W2, W3, Q8, Sc, Wt1, Wt2, Wt3p);

    // Layer 1: agg = A @ x (int8 gather) ; Q8/Sc = uint8-quant(relu(agg @ W1)) fused
    spmm_i8<0><<<RGRID, 256, 0, stream>>>(row_ptr, cp, Q8, Sc, B1);
    gemm1_quant<<<GXM, 256, 0, stream>>>(B1, Wt1, (unsigned char*)Q8, Sc, NN);

    // Layer 2+3 fused: agg = A @ h1 (uint8 gather) ; Lb = relu(agg @ W2) @ W3 (h2 in LDS only)
    spmm_i8<1><<<RGRID, 256, 0, stream>>>(row_ptr, cp, Q8, Sc, B1);
    gemm23<<<GXM, 256, 0, stream>>>(B1, Wt2, Wt3p, Lb, NN);

    // final: out = log_softmax( A @ Lb )
    spmm40_lsm<<<RGRID, 256, 0, stream>>>(row_ptr, cp, Lb, out);
}

// Round 19
// 525.425 us; speedup vs baseline: 3.9483x; 1.1382x over previous
//
#include <hip/hip_runtime.h>
#include <math.h>

#define NN 100000
#define NE 3200000
#define FD 256        // feature dim
#define NC 40         // classes
#define BN_BUCK 196   // ceil(NN / 512)

typedef unsigned int u32;
typedef __attribute__((ext_vector_type(8))) short short8;
typedef __attribute__((ext_vector_type(4))) float f32x4;

#define AS1 __attribute__((address_space(1)))
#define AS3 __attribute__((address_space(3)))

static __device__ __forceinline__ float bf2f(unsigned short h) {
    return __builtin_bit_cast(float, ((u32)h) << 16);
}
static __device__ __forceinline__ unsigned short f2bf(float f) {
    u32 u = __builtin_bit_cast(u32, f);
    u += 0x7fffu + ((u >> 16) & 1u);   // RNE
    return (unsigned short)(u >> 16);
}

// ---------------- binned CSR build (4096 edges/block batching) ----------------

__global__ __launch_bounds__(256) void bucket_count(const int* __restrict__ ei_dst, int* __restrict__ gcount) {
    __shared__ int sh[BN_BUCK];
    int t = threadIdx.x;
    if (t < BN_BUCK) sh[t] = 0;
    __syncthreads();
#pragma unroll
    for (int j = 0; j < 4; ++j) {
        int base = blockIdx.x * 4096 + j * 1024;
        if (base < NE) {
            int4 d = *reinterpret_cast<const int4*>(ei_dst + base + t * 4);
            atomicAdd(&sh[d.x >> 9], 1);
            atomicAdd(&sh[d.y >> 9], 1);
            atomicAdd(&sh[d.z >> 9], 1);
            atomicAdd(&sh[d.w >> 9], 1);
        }
    }
    __syncthreads();
    if (t < BN_BUCK && sh[t]) atomicAdd(&gcount[t], sh[t]);
}

__global__ __launch_bounds__(256) void bucket_scan(const int* __restrict__ gcount,
                                                   int* __restrict__ bucketBase,
                                                   int* __restrict__ bucketFill,
                                                   int* __restrict__ row_ptr) {
    __shared__ int s[256];
    int t = threadIdx.x;
    int v = (t < BN_BUCK) ? gcount[t] : 0;
    s[t] = v;
    __syncthreads();
    for (int d = 1; d < 256; d <<= 1) {
        int x = (t >= d) ? s[t - d] : 0;
        __syncthreads();
        s[t] += x;
        __syncthreads();
    }
    int excl = s[t] - v;
    if (t < BN_BUCK) {
        bucketBase[t] = excl;
        bucketFill[t] = excl;
    }
    if (t == 0) {
        bucketBase[BN_BUCK] = NE;
        row_ptr[NN] = NE;
    }
}

__global__ __launch_bounds__(256) void partition_edges(const int* __restrict__ ei, const float* __restrict__ ev,
                                                       int* __restrict__ bucketFill, int2* __restrict__ ebuf) {
    __shared__ int cnt[BN_BUCK];
    __shared__ int gb[BN_BUCK];
    __shared__ int fill[BN_BUCK];
    int t = threadIdx.x;
    if (t < BN_BUCK) { cnt[t] = 0; fill[t] = 0; }
    __syncthreads();
    int4 s4[4], d4[4];
    float4 v4[4];
#pragma unroll
    for (int j = 0; j < 4; ++j) {
        int base = blockIdx.x * 4096 + j * 1024;
        if (base < NE) {
            int i = base + t * 4;
            s4[j] = *reinterpret_cast<const int4*>(ei + i);
            d4[j] = *reinterpret_cast<const int4*>(ei + NE + i);
            v4[j] = *reinterpret_cast<const float4*>(ev + i);
            atomicAdd(&cnt[d4[j].x >> 9], 1);
            atomicAdd(&cnt[d4[j].y >> 9], 1);
            atomicAdd(&cnt[d4[j].z >> 9], 1);
            atomicAdd(&cnt[d4[j].w >> 9], 1);
        }
    }
    __syncthreads();
    if (t < BN_BUCK && cnt[t]) gb[t] = atomicAdd(&bucketFill[t], cnt[t]);
    __syncthreads();
#pragma unroll
    for (int j = 0; j < 4; ++j) {
        int base = blockIdx.x * 4096 + j * 1024;
        if (base < NE) {
            int b0 = d4[j].x >> 9, b1 = d4[j].y >> 9, b2 = d4[j].z >> 9, b3 = d4[j].w >> 9;
            int r;
            r = atomicAdd(&fill[b0], 1); ebuf[gb[b0] + r] = make_int2((s4[j].x << 9) | (d4[j].x & 511), __float_as_int(v4[j].x));
            r = atomicAdd(&fill[b1], 1); ebuf[gb[b1] + r] = make_int2((s4[j].y << 9) | (d4[j].y & 511), __float_as_int(v4[j].y));
            r = atomicAdd(&fill[b2], 1); ebuf[gb[b2] + r] = make_int2((s4[j].z << 9) | (d4[j].z & 511), __float_as_int(v4[j].z));
            r = atomicAdd(&fill[b3], 1); ebuf[gb[b3] + r] = make_int2((s4[j].w << 9) | (d4[j].w & 511), __float_as_int(v4[j].w));
        }
    }
}

// 512 threads: one thread per bucket-node; count -> 512-wide scan -> place
__global__ __launch_bounds__(512) void bucket_csr(const int* __restrict__ bucketBase,
                                                  const int2* __restrict__ ebuf,
                                                  int* __restrict__ row_ptr, int2* __restrict__ cp) {
    __shared__ int cnt[512];
    __shared__ int s[512];
    int b = blockIdx.x, t = threadIdx.x;
    int beg = bucketBase[b], end = bucketBase[b + 1];
    cnt[t] = 0;
    __syncthreads();
    for (int e = beg + t; e < end; e += 512)
        atomicAdd(&cnt[ebuf[e].x & 511], 1);
    __syncthreads();
    int c = cnt[t];
    s[t] = c;
    __syncthreads();
    for (int d = 1; d < 512; d <<= 1) {
        int x = (t >= d) ? s[t - d] : 0;
        __syncthreads();
        s[t] += x;
        __syncthreads();
    }
    int excl = s[t] - c;
    int g = b * 512 + t;
    if (g < NN) row_ptr[g] = beg + excl;
    __syncthreads();
    cnt[t] = excl;
    __syncthreads();
    for (int e = beg + t; e < end; e += 512) {
        int2 E = ebuf[e];
        int r = atomicAdd(&cnt[E.x & 511], 1);
        cp[beg + r] = make_int2(E.x >> 9, E.y);
    }
}

// ------- prep (merged): x -> signed int8 table + scales ; weights -> bf16 transposed -------

__global__ __launch_bounds__(256) void prep(const float* __restrict__ x,
                                            const float* __restrict__ W1,
                                            const float* __restrict__ W2,
                                            const float* __restrict__ W3,
                                            u32* __restrict__ Q, float* __restrict__ Sc,
                                            unsigned short* __restrict__ Wt1,
                                            unsigned short* __restrict__ Wt2,
                                            unsigned short* __restrict__ Wt3p) {
    int b = blockIdx.x, t = threadIdx.x;
    if (b < 25000) {
        int wv = t >> 6, l = t & 63;
        int row = b * 4 + wv;
        float4 v = reinterpret_cast<const float4*>(x)[(size_t)row * 64 + l];
        float m = fmaxf(fmaxf(fabsf(v.x), fabsf(v.y)), fmaxf(fabsf(v.z), fabsf(v.w)));
        for (int d = 32; d > 0; d >>= 1) m = fmaxf(m, __shfl_xor(m, d));
        float inv = (m > 0.f) ? 127.f / m : 0.f;
        int q0 = (int)rintf(v.x * inv), q1 = (int)rintf(v.y * inv);
        int q2 = (int)rintf(v.z * inv), q3 = (int)rintf(v.w * inv);
        u32 pk = (u32)(q0 & 255) | ((u32)(q1 & 255) << 8) | ((u32)(q2 & 255) << 16) | ((u32)(q3 & 255) << 24);
        Q[(size_t)row * 64 + l] = pk;
        if (l == 0) Sc[row] = m * (1.f / 127.f);
    } else if (b < 25256) {
        int n = b - 25000;
        Wt1[n * 256 + t] = f2bf(W1[t * 256 + n]);
    } else if (b < 25512) {
        int n = b - 25256;
        Wt2[n * 256 + t] = f2bf(W2[t * 256 + n]);
    } else {
        int n = b - 25512;
        Wt3p[n * 256 + t] = (n < NC) ? f2bf(W3[t * NC + n]) : (unsigned short)0;
    }
}

// ------- SPMM int8 (r14-proven): one wave per dst row, depth-16 main + 8 + 4 + 2 tails -------

template <int UNSIGNED>
__global__ __launch_bounds__(256) void spmm_i8(const int* __restrict__ rp,
                                               const int2* __restrict__ cp,
                                               const u32* __restrict__ Q,
                                               const float* __restrict__ Sc,
                                               unsigned short* __restrict__ O) {
    int wv = threadIdx.x >> 6;
    int l = threadIdx.x & 63;
    int row = blockIdx.x * 4 + wv;
    if (row >= NN) return;
    int beg = __builtin_amdgcn_readfirstlane(rp[row]);
    int end = __builtin_amdgcn_readfirstlane(rp[row + 1]);
    float a0 = 0.f, a1 = 0.f, a2 = 0.f, a3 = 0.f;

#define ACC_I8(W, VS)                                                            \
    {                                                                            \
        u32 w_ = (W);                                                            \
        float p0_, p1_, p2_, p3_;                                                \
        if (UNSIGNED) {                                                          \
            p0_ = (float)(w_ & 255u);        p1_ = (float)((w_ >> 8) & 255u);    \
            p2_ = (float)((w_ >> 16) & 255u); p3_ = (float)(w_ >> 24);           \
        } else {                                                                 \
            p0_ = (float)(int)(char)(w_);        p1_ = (float)(int)(char)(w_ >> 8);  \
            p2_ = (float)(int)(char)(w_ >> 16);  p3_ = (float)(int)(char)(w_ >> 24); \
        }                                                                        \
        a0 += (VS) * p0_; a1 += (VS) * p1_; a2 += (VS) * p2_; a3 += (VS) * p3_;  \
    }

    int e = beg;
    int efull = beg + ((end - beg) & ~15);
    if (e < efull) {
        int2 m[16];
        float vs[16];
#pragma unroll
        for (int j = 0; j < 16; ++j) m[j] = cp[e + j];
#pragma unroll
        for (int j = 0; j < 16; ++j) vs[j] = __int_as_float(m[j].y) * Sc[m[j].x];
        e += 16;
        for (; e < efull; e += 16) {
            u32 hv[16];
#pragma unroll
            for (int j = 0; j < 16; ++j) hv[j] = Q[(size_t)m[j].x * 64 + l];
            int2 mn[16];
            float vsn[16];
#pragma unroll
            for (int j = 0; j < 16; ++j) mn[j] = cp[e + j];
#pragma unroll
            for (int j = 0; j < 16; ++j) vsn[j] = __int_as_float(mn[j].y) * Sc[mn[j].x];
#pragma unroll
            for (int j = 0; j < 16; ++j) ACC_I8(hv[j], vs[j]);
#pragma unroll
            for (int j = 0; j < 16; ++j) { m[j] = mn[j]; vs[j] = vsn[j]; }
        }
        {
            u32 hv[16];
#pragma unroll
            for (int j = 0; j < 16; ++j) hv[j] = Q[(size_t)m[j].x * 64 + l];
#pragma unroll
            for (int j = 0; j < 16; ++j) ACC_I8(hv[j], vs[j]);
        }
    }
    if (end - e >= 8) {
        int2 m[8];
        float vs[8];
#pragma unroll
        for (int j = 0; j < 8; ++j) m[j] = cp[e + j];
#pragma unroll
        for (int j = 0; j < 8; ++j) vs[j] = __int_as_float(m[j].y) * Sc[m[j].x];
        u32 hv[8];
#pragma unroll
        for (int j = 0; j < 8; ++j) hv[j] = Q[(size_t)m[j].x * 64 + l];
#pragma unroll
        for (int j = 0; j < 8; ++j) ACC_I8(hv[j], vs[j]);
        e += 8;
    }
    if (end - e >= 4) {
        int2 m[4];
        float vs[4];
#pragma unroll
        for (int j = 0; j < 4; ++j) m[j] = cp[e + j];
#pragma unroll
        for (int j = 0; j < 4; ++j) vs[j] = __int_as_float(m[j].y) * Sc[m[j].x];
        u32 hv[4];
#pragma unroll
        for (int j = 0; j < 4; ++j) hv[j] = Q[(size_t)m[j].x * 64 + l];
#pragma unroll
        for (int j = 0; j < 4; ++j) ACC_I8(hv[j], vs[j]);
        e += 4;
    }
    if (end - e >= 2) {
        int2 m0 = cp[e];
        int2 m1 = cp[e + 1];
        float v0 = __int_as_float(m0.y) * Sc[m0.x];
        float v1 = __int_as_float(m1.y) * Sc[m1.x];
        u32 h0 = Q[(size_t)m0.x * 64 + l];
        u32 h1 = Q[(size_t)m1.x * 64 + l];
        ACC_I8(h0, v0);
        ACC_I8(h1, v1);
        e += 2;
    }
    for (; e < end; ++e) {
        int2 m1 = cp[e];
        float vs1 = __int_as_float(m1.y) * Sc[m1.x];
        u32 hv = Q[(size_t)m1.x * 64 + l];
        ACC_I8(hv, vs1);
    }
#undef ACC_I8
    ushort4 o;
    o.x = f2bf(a0); o.y = f2bf(a1); o.z = f2bf(a2); o.w = f2bf(a3);
    reinterpret_cast<ushort4*>(O)[(size_t)row * 64 + l] = o;
}

#define BM 128
#define BKK 64

// ------- GEMM1+QUANT fused (r17-proven): Q8/Sc = uint8-quant( relu( A @ Wt1 ) ) -------

__global__ __launch_bounds__(256) void gemm1_quant(const unsigned short* __restrict__ A,
                                                   const unsigned short* __restrict__ Wt,
                                                   unsigned char* __restrict__ Q8b,
                                                   float* __restrict__ Sc, int M) {
    __shared__ unsigned short As[BM * BKK];
    __shared__ unsigned short Bs[BM * BKK];
    __shared__ unsigned rmax[BM];
    int tid = threadIdx.x;
    int l = tid & 63;
    int w = tid >> 6;
    int wm = w >> 1, wn = w & 1;
    int bm = blockIdx.x * BM;
    if (tid < BM) rmax[tid] = 0u;

    f32x4 acc[4][4];
    u32 p0[4][4][2];

    for (int bh = 0; bh < 2; ++bh) {
        int bn = bh * 128;
#pragma unroll
        for (int m = 0; m < 4; ++m)
#pragma unroll
            for (int n = 0; n < 4; ++n)
                acc[m][n] = (f32x4){0.f, 0.f, 0.f, 0.f};

        for (int kt = 0; kt < 4; ++kt) {
            int k0 = kt * BKK;
#pragma unroll
            for (int i = 0; i < 4; ++i) {
                int e = i * 256 + tid;
                int row = e >> 3;
                int c = e & 7;
                int cs = c ^ (row & 7);
                int ga = min(bm + row, M - 1);
                __builtin_amdgcn_global_load_lds(
                    (const AS1 u32*)(A + (size_t)ga * 256 + k0 + cs * 8),
                    (AS3 u32*)(As + e * 8), 16, 0, 0);
                __builtin_amdgcn_global_load_lds(
                    (const AS1 u32*)(Wt + (size_t)(bn + row) * 256 + k0 + cs * 8),
                    (AS3 u32*)(Bs + e * 8), 16, 0, 0);
            }
            __syncthreads();
#pragma unroll
            for (int h = 0; h < 2; ++h) {
                short8 av[4], bv[4];
#pragma unroll
                for (int m = 0; m < 4; ++m) {
                    int row = wm * 64 + m * 16 + (l & 15);
                    int cs = (h * 4 + (l >> 4)) ^ (row & 7);
                    av[m] = *(const short8*)(As + row * BKK + cs * 8);
                }
#pragma unroll
                for (int n = 0; n < 4; ++n) {
                    int row = wn * 64 + n * 16 + (l & 15);
                    int cs = (h * 4 + (l >> 4)) ^ (row & 7);
                    bv[n] = *(const short8*)(Bs + row * BKK + cs * 8);
                }
#pragma unroll
                for (int m = 0; m < 4; ++m)
#pragma unroll
                    for (int n = 0; n < 4; ++n)
                        acc[m][n] = __builtin_amdgcn_mfma_f32_16x16x32_bf16(av[m], bv[n], acc[m][n], 0, 0, 0);
            }
            __syncthreads();
        }
        if (bh == 0) {
#pragma unroll
            for (int m = 0; m < 4; ++m)
#pragma unroll
                for (int n = 0; n < 4; ++n) {
                    float v0 = fmaxf(acc[m][n][0], 0.f);
                    float v1 = fmaxf(acc[m][n][1], 0.f);
                    float v2 = fmaxf(acc[m][n][2], 0.f);
                    float v3 = fmaxf(acc[m][n][3], 0.f);
                    p0[m][n][0] = (u32)f2bf(v0) | ((u32)f2bf(v1) << 16);
                    p0[m][n][1] = (u32)f2bf(v2) | ((u32)f2bf(v3) << 16);
                }
        }
    }

    float mx[4][4];
#pragma unroll
    for (int m = 0; m < 4; ++m)
#pragma unroll
        for (int r = 0; r < 4; ++r) {
            float v = 0.f;
#pragma unroll
            for (int n = 0; n < 4; ++n) {
                v = fmaxf(v, fmaxf(acc[m][n][r], 0.f));
                u32 pw = p0[m][n][r >> 1];
                unsigned short b = (r & 1) ? (unsigned short)(pw >> 16) : (unsigned short)(pw & 0xffff);
                v = fmaxf(v, bf2f(b));
            }
            v = fmaxf(v, __shfl_xor(v, 1));
            v = fmaxf(v, __shfl_xor(v, 2));
            v = fmaxf(v, __shfl_xor(v, 4));
            v = fmaxf(v, __shfl_xor(v, 8));
            mx[m][r] = v;
        }
    if ((l & 15) == 0) {
#pragma unroll
        for (int m = 0; m < 4; ++m)
#pragma unroll
            for (int r = 0; r < 4; ++r)
                atomicMax(&rmax[wm * 64 + m * 16 + (l >> 4) * 4 + r], __float_as_uint(mx[m][r]));
    }
    __syncthreads();

#pragma unroll
    for (int m = 0; m < 4; ++m)
#pragma unroll
        for (int r = 0; r < 4; ++r) {
            int lr = wm * 64 + m * 16 + (l >> 4) * 4 + r;
            int gr = bm + lr;
            float rm = __uint_as_float(rmax[lr]);
            float inv = (rm > 0.f) ? 255.f / rm : 0.f;
            if (gr < M) {
#pragma unroll
                for (int n = 0; n < 4; ++n) {
                    u32 pw = p0[m][n][r >> 1];
                    unsigned short b = (r & 1) ? (unsigned short)(pw >> 16) : (unsigned short)(pw & 0xffff);
                    int q0v = (int)rintf(bf2f(b) * inv);
                    int q1v = (int)rintf(fmaxf(acc[m][n][r], 0.f) * inv);
                    Q8b[(size_t)gr * 256 + wn * 64 + n * 16 + (l & 15)] = (unsigned char)q0v;
                    Q8b[(size_t)gr * 256 + 128 + wn * 64 + n * 16 + (l & 15)] = (unsigned char)q1v;
                }
                if (wn == 0 && (l & 15) == 0) Sc[gr] = rm * (1.f / 255.f);
            }
        }
}

// ------- GEMM2+GEMM3 fused (r18): Lb[M,40] = ( relu( A @ Wt2 ) ) @ W3 ; h2 in LDS only -------

__global__ __launch_bounds__(256) void gemm23(const unsigned short* __restrict__ A,
                                              const unsigned short* __restrict__ Wt2,
                                              const unsigned short* __restrict__ Wt3p,
                                              unsigned short* __restrict__ Lb, int M) {
    __shared__ unsigned short As[BM * BKK];
    __shared__ unsigned short Bs[BM * BKK];
    int tid = threadIdx.x;
    int l = tid & 63;
    int w = tid >> 6;
    int wm = w >> 1, wn = w & 1;
    int bm = blockIdx.x * BM;

    f32x4 acc[4][4];
    f32x4 acc2[2][3] = {};

    for (int bh = 0; bh < 2; ++bh) {
        int bn = bh * 128;
#pragma unroll
        for (int m = 0; m < 4; ++m)
#pragma unroll
            for (int n = 0; n < 4; ++n)
                acc[m][n] = (f32x4){0.f, 0.f, 0.f, 0.f};

        for (int kt = 0; kt < 4; ++kt) {
            int k0 = kt * BKK;
#pragma unroll
            for (int i = 0; i < 4; ++i) {
                int e = i * 256 + tid;
                int row = e >> 3;
                int c = e & 7;
                int cs = c ^ (row & 7);
                int ga = min(bm + row, M - 1);
                __builtin_amdgcn_global_load_lds(
                    (const AS1 u32*)(A + (size_t)ga * 256 + k0 + cs * 8),
                    (AS3 u32*)(As + e * 8), 16, 0, 0);
                __builtin_amdgcn_global_load_lds(
                    (const AS1 u32*)(Wt2 + (size_t)(bn + row) * 256 + k0 + cs * 8),
                    (AS3 u32*)(Bs + e * 8), 16, 0, 0);
            }
            __syncthreads();
#pragma unroll
            for (int h = 0; h < 2; ++h) {
                short8 av[4], bv[4];
#pragma unroll
                for (int m = 0; m < 4; ++m) {
                    int row = wm * 64 + m * 16 + (l & 15);
                    int cs = (h * 4 + (l >> 4)) ^ (row & 7);
                    av[m] = *(const short8*)(As + row * BKK + cs * 8);
                }
#pragma unroll
                for (int n = 0; n < 4; ++n) {
                    int row = wn * 64 + n * 16 + (l & 15);
                    int cs = (h * 4 + (l >> 4)) ^ (row & 7);
                    bv[n] = *(const short8*)(Bs + row * BKK + cs * 8);
                }
#pragma unroll
                for (int m = 0; m < 4; ++m)
#pragma unroll
                    for (int n = 0; n < 4; ++n)
                        acc[m][n] = __builtin_amdgcn_mfma_f32_16x16x32_bf16(av[m], bv[n], acc[m][n], 0, 0, 0);
            }
            __syncthreads();
        }

        {
            unsigned short* H2s = (wm == 0) ? As : Bs;
#pragma unroll
            for (int m = 0; m < 4; ++m)
#pragma unroll
                for (int r = 0; r < 4; ++r) {
                    int lr = m * 16 + (l >> 4) * 4 + r;
#pragma unroll
                    for (int n = 0; n < 4; ++n) {
                        int c = wn * 64 + n * 16 + (l & 15);
                        int cs = (c >> 3) ^ (lr & 7);
                        H2s[lr * 128 + cs * 8 + (c & 7)] = f2bf(fmaxf(acc[m][n][r], 0.f));
                    }
                }
        }
        __syncthreads();

        {
            const unsigned short* H2s = (w < 2) ? As : Bs;
            int lrow = (w & 1) * 32;
#pragma unroll
            for (int mm = 0; mm < 2; ++mm) {
                int lr = lrow + mm * 16 + (l & 15);
#pragma unroll
                for (int kc = 0; kc < 4; ++kc) {
                    int cs = (kc * 4 + (l >> 4)) ^ (lr & 7);
                    short8 av = *(const short8*)(H2s + lr * 128 + cs * 8);
#pragma unroll
                    for (int j3 = 0; j3 < 3; ++j3) {
                        const unsigned short* bp = Wt3p + (size_t)(j3 * 16 + (l & 15)) * 256 + bh * 128 + kc * 32 + (l >> 4) * 8;
                        short8 bv = *(const short8*)bp;
                        acc2[mm][j3] = __builtin_amdgcn_mfma_f32_16x16x32_bf16(av, bv, acc2[mm][j3], 0, 0, 0);
                    }
                }
            }
        }
        __syncthreads();
    }

#pragma unroll
    for (int mm = 0; mm < 2; ++mm)
#pragma unroll
        for (int j3 = 0; j3 < 3; ++j3)
#pragma unroll
            for (int r = 0; r < 4; ++r) {
                int gr = bm + w * 32 + mm * 16 + (l >> 4) * 4 + r;
                int gc = j3 * 16 + (l & 15);
                if (gr < M && gc < NC) Lb[(size_t)gr * NC + gc] = f2bf(acc2[mm][j3][r]);
            }
}

// ------- fused: out[row] = log_softmax( sum_e val * Lb[src] ), depth 16 + 8 + 4 + 2 tails -------

__global__ __launch_bounds__(256) void spmm40_lsm(const int* __restrict__ rp,
                                                  const int2* __restrict__ cp,
                                                  const unsigned short* __restrict__ Lb,
                                                  float* __restrict__ out) {
    int wv = threadIdx.x >> 6, l = threadIdx.x & 63;
    int row = blockIdx.x * 4 + wv;
    if (row >= NN) return;
    int beg = __builtin_amdgcn_readfirstlane(rp[row]);
    int end = __builtin_amdgcn_readfirstlane(rp[row + 1]);
    int lc = min(l, NC - 1);
    float acc = 0.f;
    int e = beg;
    int efull = beg + ((end - beg) & ~15);
    if (e < efull) {
        int2 m[16];
#pragma unroll
        for (int j = 0; j < 16; ++j) m[j] = cp[e + j];
        e += 16;
        for (; e < efull; e += 16) {
            unsigned short hv[16];
#pragma unroll
            for (int j = 0; j < 16; ++j) hv[j] = Lb[(size_t)m[j].x * NC + lc];
            int2 mn[16];
#pragma unroll
            for (int j = 0; j < 16; ++j) mn[j] = cp[e + j];
#pragma unroll
            for (int j = 0; j < 16; ++j)
                acc += __int_as_float(m[j].y) * bf2f(hv[j]);
#pragma unroll
            for (int j = 0; j < 16; ++j) m[j] = mn[j];
        }
        {
            unsigned short hv[16];
#pragma unroll
            for (int j = 0; j < 16; ++j) hv[j] = Lb[(size_t)m[j].x * NC + lc];
#pragma unroll
            for (int j = 0; j < 16; ++j)
                acc += __int_as_float(m[j].y) * bf2f(hv[j]);
        }
    }
    if (end - e >= 8) {
        int2 m[8];
#pragma unroll
        for (int j = 0; j < 8; ++j) m[j] = cp[e + j];
        unsigned short hv[8];
#pragma unroll
        for (int j = 0; j < 8; ++j) hv[j] = Lb[(size_t)m[j].x * NC + lc];
#pragma unroll
        for (int j = 0; j < 8; ++j)
            acc += __int_as_float(m[j].y) * bf2f(hv[j]);
        e += 8;
    }
    if (end - e >= 4) {
        int2 m[4];
#pragma unroll
        for (int j = 0; j < 4; ++j) m[j] = cp[e + j];
        unsigned short hv[4];
#pragma unroll
        for (int j = 0; j < 4; ++j) hv[j] = Lb[(size_t)m[j].x * NC + lc];
#pragma unroll
        for (int j = 0; j < 4; ++j)
            acc += __int_as_float(m[j].y) * bf2f(hv[j]);
        e += 4;
    }
    if (end - e >= 2) {
        int2 m0 = cp[e];
        int2 m1 = cp[e + 1];
        unsigned short h0 = Lb[(size_t)m0.x * NC + lc];
        unsigned short h1 = Lb[(size_t)m1.x * NC + lc];
        acc += __int_as_float(m0.y) * bf2f(h0);
        acc += __int_as_float(m1.y) * bf2f(h1);
        e += 2;
    }
    for (; e < end; ++e) {
        int2 m1 = cp[e];
        acc += __int_as_float(m1.y) * bf2f(Lb[(size_t)m1.x * NC + lc]);
    }
    float v = (l < NC) ? acc : -INFINITY;
    float mx = v;
    for (int d = 32; d > 0; d >>= 1) mx = fmaxf(mx, __shfl_xor(mx, d));
    float ex = (l < NC) ? expf(v - mx) : 0.f;
    float ssum = ex;
    for (int d = 32; d > 0; d >>= 1) ssum += __shfl_xor(ssum, d);
    float ls = logf(ssum);
    if (l < NC) out[(size_t)row * NC + l] = v - mx - ls;
}

// ---------------- launch ----------------

extern "C" void kernel_launch(void* const* d_in, const int* in_sizes, int n_in,
                              void* d_out, int out_size, void* d_ws, size_t ws_size,
                              hipStream_t stream) {
    const float* x  = (const float*)d_in[0];
    const int*   ei = (const int*)d_in[1];
    const float* ev = (const float*)d_in[2];
    const float* W1 = (const float*)d_in[3];
    const float* W2 = (const float*)d_in[4];
    const float* W3 = (const float*)d_in[5];
    float* out = (float*)d_out;

    char* ws = (char*)d_ws;
    size_t o = 0;
    unsigned short* B1 = (unsigned short*)(ws + o); o += (size_t)NN * FD * 2;   // 51.2 MB agg (aliases ebuf)
    u32*   Q8          = (u32*)(ws + o);            o += (size_t)NN * FD;       // 25.6 MB int8 table
    float* Sc          = (float*)(ws + o);          o += (size_t)NN * 4;        // 400 KB scales
    unsigned short* Lb = (unsigned short*)(ws + o); o += (size_t)NN * NC * 2;   // 8 MB
    int2*  cp          = (int2*)(ws + o);           o += (size_t)NE * 8;        // 25.6 MB
    int*   row_ptr     = (int*)(ws + o);            o += 400128;
    int*   gcount      = (int*)(ws + o);            o += 1024;
    int*   bucketBase  = (int*)(ws + o);            o += 1024;
    int*   bucketFill  = (int*)(ws + o);            o += 1024;
    unsigned short* Wt1  = (unsigned short*)(ws + o); o += 256 * 256 * 2;
    unsigned short* Wt2  = (unsigned short*)(ws + o); o += 256 * 256 * 2;
    unsigned short* Wt3p = (unsigned short*)(ws + o); o += 48 * 256 * 2;

    int2* ebuf = (int2*)B1;   // lifetime: partition_edges..bucket_csr, before B1's first write

    const int EB4   = (NE + 4095) / 4096;         // 782 (4096 edges/block, chunk-guarded)
    const int RGRID = (NN + 3) / 4;               // 25000
    const int GXM   = (NN + BM - 1) / BM;         // 782

    // binned CSR build
    hipMemsetAsync(gcount, 0, BN_BUCK * sizeof(int), stream);
    bucket_count<<<EB4, 256, 0, stream>>>(ei + NE, gcount);
    bucket_scan<<<1, 256, 0, stream>>>(gcount, bucketBase, bucketFill, row_ptr);
    partition_edges<<<EB4, 256, 0, stream>>>(ei, ev, bucketFill, ebuf);
    bucket_csr<<<BN_BUCK, 512, 0, stream>>>(bucketBase, ebuf, row_ptr, cp);

    // prep (merged): x -> int8 + scales, weights transposed bf16
    prep<<<25560, 256, 0, stream>>>(x, W1, W2, W3, Q8, Sc, Wt1, Wt2, Wt3p);

    // Layer 1: agg = A @ x (int8 gather) ; Q8/Sc = uint8-quant(relu(agg @ W1)) fused
    spmm_i8<0><<<RGRID, 256, 0, stream>>>(row_ptr, cp, Q8, Sc, B1);
    gemm1_quant<<<GXM, 256, 0, stream>>>(B1, Wt1, (unsigned char*)Q8, Sc, NN);

    // Layer 2+3 fused: agg = A @ h1 (uint8 gather) ; Lb = relu(agg @ W2) @ W3 (h2 in LDS only)
    spmm_i8<1><<<RGRID, 256, 0, stream>>>(row_ptr, cp, Q8, Sc, B1);
    gemm23<<<GXM, 256, 0, stream>>>(B1, Wt2, Wt3p, Lb, NN);

    // final: out = log_softmax( A @ Lb )
    spmm40_lsm<<<RGRID, 256, 0, stream>>>(row_ptr, cp, Lb, out);
}

// Round 20
// 523.175 us; speedup vs baseline: 3.9653x; 1.0043x over previous
//
#include <hip/hip_runtime.h>
#include <math.h>

#define NN 100000
#define NE 3200000
#define FD 256        // feature dim
#define NC 40         // classes
#define BN_BUCK 196   // ceil(NN / 512)

typedef unsigned int u32;
typedef __attribute__((ext_vector_type(8))) short short8;
typedef __attribute__((ext_vector_type(4))) float f32x4;

#define AS1 __attribute__((address_space(1)))
#define AS3 __attribute__((address_space(3)))

static __device__ __forceinline__ float bf2f(unsigned short h) {
    return __builtin_bit_cast(float, ((u32)h) << 16);
}
static __device__ __forceinline__ unsigned short f2bf(float f) {
    u32 u = __builtin_bit_cast(u32, f);
    u += 0x7fffu + ((u >> 16) & 1u);   // RNE
    return (unsigned short)(u >> 16);
}

// ---------------- binned CSR build (8192 edges/block batching) ----------------

__global__ __launch_bounds__(256) void bucket_count(const int* __restrict__ ei_dst, int* __restrict__ gcount) {
    __shared__ int sh[BN_BUCK];
    int t = threadIdx.x;
    if (t < BN_BUCK) sh[t] = 0;
    __syncthreads();
#pragma unroll
    for (int j = 0; j < 8; ++j) {
        int base = blockIdx.x * 8192 + j * 1024;
        if (base < NE) {
            int4 d = *reinterpret_cast<const int4*>(ei_dst + base + t * 4);
            atomicAdd(&sh[d.x >> 9], 1);
            atomicAdd(&sh[d.y >> 9], 1);
            atomicAdd(&sh[d.z >> 9], 1);
            atomicAdd(&sh[d.w >> 9], 1);
        }
    }
    __syncthreads();
    if (t < BN_BUCK && sh[t]) atomicAdd(&gcount[t], sh[t]);
}

__global__ __launch_bounds__(256) void bucket_scan(const int* __restrict__ gcount,
                                                   int* __restrict__ bucketBase,
                                                   int* __restrict__ bucketFill,
                                                   int* __restrict__ row_ptr) {
    __shared__ int s[256];
    int t = threadIdx.x;
    int v = (t < BN_BUCK) ? gcount[t] : 0;
    s[t] = v;
    __syncthreads();
    for (int d = 1; d < 256; d <<= 1) {
        int x = (t >= d) ? s[t - d] : 0;
        __syncthreads();
        s[t] += x;
        __syncthreads();
    }
    int excl = s[t] - v;
    if (t < BN_BUCK) {
        bucketBase[t] = excl;
        bucketFill[t] = excl;
    }
    if (t == 0) {
        bucketBase[BN_BUCK] = NE;
        row_ptr[NN] = NE;
    }
}

// 8192 edges/block; count phase reads dst only, scatter phase reloads (no regs held across barrier)
__global__ __launch_bounds__(256) void partition_edges(const int* __restrict__ ei, const float* __restrict__ ev,
                                                       int* __restrict__ bucketFill, int2* __restrict__ ebuf) {
    __shared__ int cnt[BN_BUCK];
    __shared__ int gb[BN_BUCK];
    __shared__ int fill[BN_BUCK];
    int t = threadIdx.x;
    if (t < BN_BUCK) { cnt[t] = 0; fill[t] = 0; }
    __syncthreads();
#pragma unroll
    for (int j = 0; j < 8; ++j) {
        int base = blockIdx.x * 8192 + j * 1024;
        if (base < NE) {
            int4 d = *reinterpret_cast<const int4*>(ei + NE + base + t * 4);
            atomicAdd(&cnt[d.x >> 9], 1);
            atomicAdd(&cnt[d.y >> 9], 1);
            atomicAdd(&cnt[d.z >> 9], 1);
            atomicAdd(&cnt[d.w >> 9], 1);
        }
    }
    __syncthreads();
    if (t < BN_BUCK && cnt[t]) gb[t] = atomicAdd(&bucketFill[t], cnt[t]);
    __syncthreads();
#pragma unroll
    for (int j = 0; j < 8; ++j) {
        int base = blockIdx.x * 8192 + j * 1024;
        if (base < NE) {
            int i = base + t * 4;
            int4 s4 = *reinterpret_cast<const int4*>(ei + i);
            int4 d4 = *reinterpret_cast<const int4*>(ei + NE + i);
            float4 v4 = *reinterpret_cast<const float4*>(ev + i);
            int b0 = d4.x >> 9, b1 = d4.y >> 9, b2 = d4.z >> 9, b3 = d4.w >> 9;
            int r;
            r = atomicAdd(&fill[b0], 1); ebuf[gb[b0] + r] = make_int2((s4.x << 9) | (d4.x & 511), __float_as_int(v4.x));
            r = atomicAdd(&fill[b1], 1); ebuf[gb[b1] + r] = make_int2((s4.y << 9) | (d4.y & 511), __float_as_int(v4.y));
            r = atomicAdd(&fill[b2], 1); ebuf[gb[b2] + r] = make_int2((s4.z << 9) | (d4.z & 511), __float_as_int(v4.z));
            r = atomicAdd(&fill[b3], 1); ebuf[gb[b3] + r] = make_int2((s4.w << 9) | (d4.w & 511), __float_as_int(v4.w));
        }
    }
}

// 512 threads: one thread per bucket-node; count -> 512-wide scan -> place
__global__ __launch_bounds__(512) void bucket_csr(const int* __restrict__ bucketBase,
                                                  const int2* __restrict__ ebuf,
                                                  int* __restrict__ row_ptr, int2* __restrict__ cp) {
    __shared__ int cnt[512];
    __shared__ int s[512];
    int b = blockIdx.x, t = threadIdx.x;
    int beg = bucketBase[b], end = bucketBase[b + 1];
    cnt[t] = 0;
    __syncthreads();
    for (int e = beg + t; e < end; e += 512)
        atomicAdd(&cnt[ebuf[e].x & 511], 1);
    __syncthreads();
    int c = cnt[t];
    s[t] = c;
    __syncthreads();
    for (int d = 1; d < 512; d <<= 1) {
        int x = (t >= d) ? s[t - d] : 0;
        __syncthreads();
        s[t] += x;
        __syncthreads();
    }
    int excl = s[t] - c;
    int g = b * 512 + t;
    if (g < NN) row_ptr[g] = beg + excl;
    __syncthreads();
    cnt[t] = excl;
    __syncthreads();
    for (int e = beg + t; e < end; e += 512) {
        int2 E = ebuf[e];
        int r = atomicAdd(&cnt[E.x & 511], 1);
        cp[beg + r] = make_int2(E.x >> 9, E.y);
    }
}

// ------- prep (merged): x -> signed int8 table + scales ; weights -> bf16 transposed -------

__global__ __launch_bounds__(256) void prep(const float* __restrict__ x,
                                            const float* __restrict__ W1,
                                            const float* __restrict__ W2,
                                            const float* __restrict__ W3,
                                            u32* __restrict__ Q, float* __restrict__ Sc,
                                            unsigned short* __restrict__ Wt1,
                                            unsigned short* __restrict__ Wt2,
                                            unsigned short* __restrict__ Wt3p) {
    int b = blockIdx.x, t = threadIdx.x;
    if (b < 25000) {
        int wv = t >> 6, l = t & 63;
        int row = b * 4 + wv;
        float4 v = reinterpret_cast<const float4*>(x)[(size_t)row * 64 + l];
        float m = fmaxf(fmaxf(fabsf(v.x), fabsf(v.y)), fmaxf(fabsf(v.z), fabsf(v.w)));
        for (int d = 32; d > 0; d >>= 1) m = fmaxf(m, __shfl_xor(m, d));
        float inv = (m > 0.f) ? 127.f / m : 0.f;
        int q0 = (int)rintf(v.x * inv), q1 = (int)rintf(v.y * inv);
        int q2 = (int)rintf(v.z * inv), q3 = (int)rintf(v.w * inv);
        u32 pk = (u32)(q0 & 255) | ((u32)(q1 & 255) << 8) | ((u32)(q2 & 255) << 16) | ((u32)(q3 & 255) << 24);
        Q[(size_t)row * 64 + l] = pk;
        if (l == 0) Sc[row] = m * (1.f / 127.f);
    } else if (b < 25256) {
        int n = b - 25000;
        Wt1[n * 256 + t] = f2bf(W1[t * 256 + n]);
    } else if (b < 25512) {
        int n = b - 25256;
        Wt2[n * 256 + t] = f2bf(W2[t * 256 + n]);
    } else {
        int n = b - 25512;
        Wt3p[n * 256 + t] = (n < NC) ? f2bf(W3[t * NC + n]) : (unsigned short)0;
    }
}

// ------- SPMM int8 (r14-proven): one wave per dst row, depth-16 main + 8 + 4 + 2 tails -------

template <int UNSIGNED>
__global__ __launch_bounds__(256) void spmm_i8(const int* __restrict__ rp,
                                               const int2* __restrict__ cp,
                                               const u32* __restrict__ Q,
                                               const float* __restrict__ Sc,
                                               unsigned short* __restrict__ O) {
    int wv = threadIdx.x >> 6;
    int l = threadIdx.x & 63;
    int row = blockIdx.x * 4 + wv;
    if (row >= NN) return;
    int beg = __builtin_amdgcn_readfirstlane(rp[row]);
    int end = __builtin_amdgcn_readfirstlane(rp[row + 1]);
    float a0 = 0.f, a1 = 0.f, a2 = 0.f, a3 = 0.f;

#define ACC_I8(W, VS)                                                            \
    {                                                                            \
        u32 w_ = (W);                                                            \
        float p0_, p1_, p2_, p3_;                                                \
        if (UNSIGNED) {                                                          \
            p0_ = (float)(w_ & 255u);        p1_ = (float)((w_ >> 8) & 255u);    \
            p2_ = (float)((w_ >> 16) & 255u); p3_ = (float)(w_ >> 24);           \
        } else {                                                                 \
            p0_ = (float)(int)(char)(w_);        p1_ = (float)(int)(char)(w_ >> 8);  \
            p2_ = (float)(int)(char)(w_ >> 16);  p3_ = (float)(int)(char)(w_ >> 24); \
        }                                                                        \
        a0 += (VS) * p0_; a1 += (VS) * p1_; a2 += (VS) * p2_; a3 += (VS) * p3_;  \
    }

    int e = beg;
    int efull = beg + ((end - beg) & ~15);
    if (e < efull) {
        int2 m[16];
        float vs[16];
#pragma unroll
        for (int j = 0; j < 16; ++j) m[j] = cp[e + j];
#pragma unroll
        for (int j = 0; j < 16; ++j) vs[j] = __int_as_float(m[j].y) * Sc[m[j].x];
        e += 16;
        for (; e < efull; e += 16) {
            u32 hv[16];
#pragma unroll
            for (int j = 0; j < 16; ++j) hv[j] = Q[(size_t)m[j].x * 64 + l];
            int2 mn[16];
            float vsn[16];
#pragma unroll
            for (int j = 0; j < 16; ++j) mn[j] = cp[e + j];
#pragma unroll
            for (int j = 0; j < 16; ++j) vsn[j] = __int_as_float(mn[j].y) * Sc[mn[j].x];
#pragma unroll
            for (int j = 0; j < 16; ++j) ACC_I8(hv[j], vs[j]);
#pragma unroll
            for (int j = 0; j < 16; ++j) { m[j] = mn[j]; vs[j] = vsn[j]; }
        }
        {
            u32 hv[16];
#pragma unroll
            for (int j = 0; j < 16; ++j) hv[j] = Q[(size_t)m[j].x * 64 + l];
#pragma unroll
            for (int j = 0; j < 16; ++j) ACC_I8(hv[j], vs[j]);
        }
    }
    if (end - e >= 8) {
        int2 m[8];
        float vs[8];
#pragma unroll
        for (int j = 0; j < 8; ++j) m[j] = cp[e + j];
#pragma unroll
        for (int j = 0; j < 8; ++j) vs[j] = __int_as_float(m[j].y) * Sc[m[j].x];
        u32 hv[8];
#pragma unroll
        for (int j = 0; j < 8; ++j) hv[j] = Q[(size_t)m[j].x * 64 + l];
#pragma unroll
        for (int j = 0; j < 8; ++j) ACC_I8(hv[j], vs[j]);
        e += 8;
    }
    if (end - e >= 4) {
        int2 m[4];
        float vs[4];
#pragma unroll
        for (int j = 0; j < 4; ++j) m[j] = cp[e + j];
#pragma unroll
        for (int j = 0; j < 4; ++j) vs[j] = __int_as_float(m[j].y) * Sc[m[j].x];
        u32 hv[4];
#pragma unroll
        for (int j = 0; j < 4; ++j) hv[j] = Q[(size_t)m[j].x * 64 + l];
#pragma unroll
        for (int j = 0; j < 4; ++j) ACC_I8(hv[j], vs[j]);
        e += 4;
    }
    if (end - e >= 2) {
        int2 m0 = cp[e];
        int2 m1 = cp[e + 1];
        float v0 = __int_as_float(m0.y) * Sc[m0.x];
        float v1 = __int_as_float(m1.y) * Sc[m1.x];
        u32 h0 = Q[(size_t)m0.x * 64 + l];
        u32 h1 = Q[(size_t)m1.x * 64 + l];
        ACC_I8(h0, v0);
        ACC_I8(h1, v1);
        e += 2;
    }
    for (; e < end; ++e) {
        int2 m1 = cp[e];
        float vs1 = __int_as_float(m1.y) * Sc[m1.x];
        u32 hv = Q[(size_t)m1.x * 64 + l];
        ACC_I8(hv, vs1);
    }
#undef ACC_I8
    ushort4 o;
    o.x = f2bf(a0); o.y = f2bf(a1); o.z = f2bf(a2); o.w = f2bf(a3);
    reinterpret_cast<ushort4*>(O)[(size_t)row * 64 + l] = o;
}

#define BM 128
#define BKK 64

// ------- GEMM1+QUANT fused (r17-proven): Q8/Sc = uint8-quant( relu( A @ Wt1 ) ) -------

__global__ __launch_bounds__(256) void gemm1_quant(const unsigned short* __restrict__ A,
                                                   const unsigned short* __restrict__ Wt,
                                                   unsigned char* __restrict__ Q8b,
                                                   float* __restrict__ Sc, int M) {
    __shared__ unsigned short As[BM * BKK];
    __shared__ unsigned short Bs[BM * BKK];
    __shared__ unsigned rmax[BM];
    int tid = threadIdx.x;
    int l = tid & 63;
    int w = tid >> 6;
    int wm = w >> 1, wn = w & 1;
    int bm = blockIdx.x * BM;
    if (tid < BM) rmax[tid] = 0u;

    f32x4 acc[4][4];
    u32 p0[4][4][2];

    for (int bh = 0; bh < 2; ++bh) {
        int bn = bh * 128;
#pragma unroll
        for (int m = 0; m < 4; ++m)
#pragma unroll
            for (int n = 0; n < 4; ++n)
                acc[m][n] = (f32x4){0.f, 0.f, 0.f, 0.f};

        for (int kt = 0; kt < 4; ++kt) {
            int k0 = kt * BKK;
#pragma unroll
            for (int i = 0; i < 4; ++i) {
                int e = i * 256 + tid;
                int row = e >> 3;
                int c = e & 7;
                int cs = c ^ (row & 7);
                int ga = min(bm + row, M - 1);
                __builtin_amdgcn_global_load_lds(
                    (const AS1 u32*)(A + (size_t)ga * 256 + k0 + cs * 8),
                    (AS3 u32*)(As + e * 8), 16, 0, 0);
                __builtin_amdgcn_global_load_lds(
                    (const AS1 u32*)(Wt + (size_t)(bn + row) * 256 + k0 + cs * 8),
                    (AS3 u32*)(Bs + e * 8), 16, 0, 0);
            }
            __syncthreads();
#pragma unroll
            for (int h = 0; h < 2; ++h) {
                short8 av[4], bv[4];
#pragma unroll
                for (int m = 0; m < 4; ++m) {
                    int row = wm * 64 + m * 16 + (l & 15);
                    int cs = (h * 4 + (l >> 4)) ^ (row & 7);
                    av[m] = *(const short8*)(As + row * BKK + cs * 8);
                }
#pragma unroll
                for (int n = 0; n < 4; ++n) {
                    int row = wn * 64 + n * 16 + (l & 15);
                    int cs = (h * 4 + (l >> 4)) ^ (row & 7);
                    bv[n] = *(const short8*)(Bs + row * BKK + cs * 8);
                }
#pragma unroll
                for (int m = 0; m < 4; ++m)
#pragma unroll
                    for (int n = 0; n < 4; ++n)
                        acc[m][n] = __builtin_amdgcn_mfma_f32_16x16x32_bf16(av[m], bv[n], acc[m][n], 0, 0, 0);
            }
            __syncthreads();
        }
        if (bh == 0) {
#pragma unroll
            for (int m = 0; m < 4; ++m)
#pragma unroll
                for (int n = 0; n < 4; ++n) {
                    float v0 = fmaxf(acc[m][n][0], 0.f);
                    float v1 = fmaxf(acc[m][n][1], 0.f);
                    float v2 = fmaxf(acc[m][n][2], 0.f);
                    float v3 = fmaxf(acc[m][n][3], 0.f);
                    p0[m][n][0] = (u32)f2bf(v0) | ((u32)f2bf(v1) << 16);
                    p0[m][n][1] = (u32)f2bf(v2) | ((u32)f2bf(v3) << 16);
                }
        }
    }

    float mx[4][4];
#pragma unroll
    for (int m = 0; m < 4; ++m)
#pragma unroll
        for (int r = 0; r < 4; ++r) {
            float v = 0.f;
#pragma unroll
            for (int n = 0; n < 4; ++n) {
                v = fmaxf(v, fmaxf(acc[m][n][r], 0.f));
                u32 pw = p0[m][n][r >> 1];
                unsigned short b = (r & 1) ? (unsigned short)(pw >> 16) : (unsigned short)(pw & 0xffff);
                v = fmaxf(v, bf2f(b));
            }
            v = fmaxf(v, __shfl_xor(v, 1));
            v = fmaxf(v, __shfl_xor(v, 2));
            v = fmaxf(v, __shfl_xor(v, 4));
            v = fmaxf(v, __shfl_xor(v, 8));
            mx[m][r] = v;
        }
    if ((l & 15) == 0) {
#pragma unroll
        for (int m = 0; m < 4; ++m)
#pragma unroll
            for (int r = 0; r < 4; ++r)
                atomicMax(&rmax[wm * 64 + m * 16 + (l >> 4) * 4 + r], __float_as_uint(mx[m][r]));
    }
    __syncthreads();

#pragma unroll
    for (int m = 0; m < 4; ++m)
#pragma unroll
        for (int r = 0; r < 4; ++r) {
            int lr = wm * 64 + m * 16 + (l >> 4) * 4 + r;
            int gr = bm + lr;
            float rm = __uint_as_float(rmax[lr]);
            float inv = (rm > 0.f) ? 255.f / rm : 0.f;
            if (gr < M) {
#pragma unroll
                for (int n = 0; n < 4; ++n) {
                    u32 pw = p0[m][n][r >> 1];
                    unsigned short b = (r & 1) ? (unsigned short)(pw >> 16) : (unsigned short)(pw & 0xffff);
                    int q0v = (int)rintf(bf2f(b) * inv);
                    int q1v = (int)rintf(fmaxf(acc[m][n][r], 0.f) * inv);
                    Q8b[(size_t)gr * 256 + wn * 64 + n * 16 + (l & 15)] = (unsigned char)q0v;
                    Q8b[(size_t)gr * 256 + 128 + wn * 64 + n * 16 + (l & 15)] = (unsigned char)q1v;
                }
                if (wn == 0 && (l & 15) == 0) Sc[gr] = rm * (1.f / 255.f);
            }
        }
}

// ------- GEMM2+GEMM3 fused (r18): Lb[M,40] = ( relu( A @ Wt2 ) ) @ W3 ; h2 in LDS only -------

__global__ __launch_bounds__(256) void gemm23(const unsigned short* __restrict__ A,
                                              const unsigned short* __restrict__ Wt2,
                                              const unsigned short* __restrict__ Wt3p,
                                              unsigned short* __restrict__ Lb, int M) {
    __shared__ unsigned short As[BM * BKK];
    __shared__ unsigned short Bs[BM * BKK];
    int tid = threadIdx.x;
    int l = tid & 63;
    int w = tid >> 6;
    int wm = w >> 1, wn = w & 1;
    int bm = blockIdx.x * BM;

    f32x4 acc[4][4];
    f32x4 acc2[2][3] = {};

    for (int bh = 0; bh < 2; ++bh) {
        int bn = bh * 128;
#pragma unroll
        for (int m = 0; m < 4; ++m)
#pragma unroll
            for (int n = 0; n < 4; ++n)
                acc[m][n] = (f32x4){0.f, 0.f, 0.f, 0.f};

        for (int kt = 0; kt < 4; ++kt) {
            int k0 = kt * BKK;
#pragma unroll
            for (int i = 0; i < 4; ++i) {
                int e = i * 256 + tid;
                int row = e >> 3;
                int c = e & 7;
                int cs = c ^ (row & 7);
                int ga = min(bm + row, M - 1);
                __builtin_amdgcn_global_load_lds(
                    (const AS1 u32*)(A + (size_t)ga * 256 + k0 + cs * 8),
                    (AS3 u32*)(As + e * 8), 16, 0, 0);
                __builtin_amdgcn_global_load_lds(
                    (const AS1 u32*)(Wt2 + (size_t)(bn + row) * 256 + k0 + cs * 8),
                    (AS3 u32*)(Bs + e * 8), 16, 0, 0);
            }
            __syncthreads();
#pragma unroll
            for (int h = 0; h < 2; ++h) {
                short8 av[4], bv[4];
#pragma unroll
                for (int m = 0; m < 4; ++m) {
                    int row = wm * 64 + m * 16 + (l & 15);
                    int cs = (h * 4 + (l >> 4)) ^ (row & 7);
                    av[m] = *(const short8*)(As + row * BKK + cs * 8);
                }
#pragma unroll
                for (int n = 0; n < 4; ++n) {
                    int row = wn * 64 + n * 16 + (l & 15);
                    int cs = (h * 4 + (l >> 4)) ^ (row & 7);
                    bv[n] = *(const short8*)(Bs + row * BKK + cs * 8);
                }
#pragma unroll
                for (int m = 0; m < 4; ++m)
#pragma unroll
                    for (int n = 0; n < 4; ++n)
                        acc[m][n] = __builtin_amdgcn_mfma_f32_16x16x32_bf16(av[m], bv[n], acc[m][n], 0, 0, 0);
            }
            __syncthreads();
        }

        {
            unsigned short* H2s = (wm == 0) ? As : Bs;
#pragma unroll
            for (int m = 0; m < 4; ++m)
#pragma unroll
                for (int r = 0; r < 4; ++r) {
                    int lr = m * 16 + (l >> 4) * 4 + r;
#pragma unroll
                    for (int n = 0; n < 4; ++n) {
                        int c = wn * 64 + n * 16 + (l & 15);
                        int cs = (c >> 3) ^ (lr & 7);
                        H2s[lr * 128 + cs * 8 + (c & 7)] = f2bf(fmaxf(acc[m][n][r], 0.f));
                    }
                }
        }
        __syncthreads();

        {
            const unsigned short* H2s = (w < 2) ? As : Bs;
            int lrow = (w & 1) * 32;
#pragma unroll
            for (int mm = 0; mm < 2; ++mm) {
                int lr = lrow + mm * 16 + (l & 15);
#pragma unroll
                for (int kc = 0; kc < 4; ++kc) {
                    int cs = (kc * 4 + (l >> 4)) ^ (lr & 7);
                    short8 av = *(const short8*)(H2s + lr * 128 + cs * 8);
#pragma unroll
                    for (int j3 = 0; j3 < 3; ++j3) {
                        const unsigned short* bp = Wt3p + (size_t)(j3 * 16 + (l & 15)) * 256 + bh * 128 + kc * 32 + (l >> 4) * 8;
                        short8 bv = *(const short8*)bp;
                        acc2[mm][j3] = __builtin_amdgcn_mfma_f32_16x16x32_bf16(av, bv, acc2[mm][j3], 0, 0, 0);
                    }
                }
            }
        }
        __syncthreads();
    }

#pragma unroll
    for (int mm = 0; mm < 2; ++mm)
#pragma unroll
        for (int j3 = 0; j3 < 3; ++j3)
#pragma unroll
            for (int r = 0; r < 4; ++r) {
                int gr = bm + w * 32 + mm * 16 + (l >> 4) * 4 + r;
                int gc = j3 * 16 + (l & 15);
                if (gr < M && gc < NC) Lb[(size_t)gr * NC + gc] = f2bf(acc2[mm][j3][r]);
            }
}

// ------- fused: out[row] = log_softmax( sum_e val * Lb[src] ), depth 16 + 8 + 4 + 2 tails -------

__global__ __launch_bounds__(256) void spmm40_lsm(const int* __restrict__ rp,
                                                  const int2* __restrict__ cp,
                                                  const unsigned short* __restrict__ Lb,
                                                  float* __restrict__ out) {
    int wv = threadIdx.x >> 6, l = threadIdx.x & 63;
    int row = blockIdx.x * 4 + wv;
    if (row >= NN) return;
    int beg = __builtin_amdgcn_readfirstlane(rp[row]);
    int end = __builtin_amdgcn_readfirstlane(rp[row + 1]);
    int lc = min(l, NC - 1);
    float acc = 0.f;
    int e = beg;
    int efull = beg + ((end - beg) & ~15);
    if (e < efull) {
        int2 m[16];
#pragma unroll
        for (int j = 0; j < 16; ++j) m[j] = cp[e + j];
        e += 16;
        for (; e < efull; e += 16) {
            unsigned short hv[16];
#pragma unroll
            for (int j = 0; j < 16; ++j) hv[j] = Lb[(size_t)m[j].x * NC + lc];
            int2 mn[16];
#pragma unroll
            for (int j = 0; j < 16; ++j) mn[j] = cp[e + j];
#pragma unroll
            for (int j = 0; j < 16; ++j)
                acc += __int_as_float(m[j].y) * bf2f(hv[j]);
#pragma unroll
            for (int j = 0; j < 16; ++j) m[j] = mn[j];
        }
        {
            unsigned short hv[16];
#pragma unroll
            for (int j = 0; j < 16; ++j) hv[j] = Lb[(size_t)m[j].x * NC + lc];
#pragma unroll
            for (int j = 0; j < 16; ++j)
                acc += __int_as_float(m[j].y) * bf2f(hv[j]);
        }
    }
    if (end - e >= 8) {
        int2 m[8];
#pragma unroll
        for (int j = 0; j < 8; ++j) m[j] = cp[e + j];
        unsigned short hv[8];
#pragma unroll
        for (int j = 0; j < 8; ++j) hv[j] = Lb[(size_t)m[j].x * NC + lc];
#pragma unroll
        for (int j = 0; j < 8; ++j)
            acc += __int_as_float(m[j].y) * bf2f(hv[j]);
        e += 8;
    }
    if (end - e >= 4) {
        int2 m[4];
#pragma unroll
        for (int j = 0; j < 4; ++j) m[j] = cp[e + j];
        unsigned short hv[4];
#pragma unroll
        for (int j = 0; j < 4; ++j) hv[j] = Lb[(size_t)m[j].x * NC + lc];
#pragma unroll
        for (int j = 0; j < 4; ++j)
            acc += __int_as_float(m[j].y) * bf2f(hv[j]);
        e += 4;
    }
    if (end - e >= 2) {
        int2 m0 = cp[e];
        int2 m1 = cp[e + 1];
        unsigned short h0 = Lb[(size_t)m0.x * NC + lc];
        unsigned short h1 = Lb[(size_t)m1.x * NC + lc];
        acc += __int_as_float(m0.y) * bf2f(h0);
        acc += __int_as_float(m1.y) * bf2f(h1);
        e += 2;
    }
    for (; e < end; ++e) {
        int2 m1 = cp[e];
        acc += __int_as_float(m1.y) * bf2f(Lb[(size_t)m1.x * NC + lc]);
    }
    float v = (l < NC) ? acc : -INFINITY;
    float mx = v;
    for (int d = 32; d > 0; d >>= 1) mx = fmaxf(mx, __shfl_xor(mx, d));
    float ex = (l < NC) ? expf(v - mx) : 0.f;
    float ssum = ex;
    for (int d = 32; d > 0; d >>= 1) ssum += __shfl_xor(ssum, d);
    float ls = logf(ssum);
    if (l < NC) out[(size_t)row * NC + l] = v - mx - ls;
}

// ---------------- launch ----------------

extern "C" void kernel_launch(void* const* d_in, const int* in_sizes, int n_in,
                              void* d_out, int out_size, void* d_ws, size_t ws_size,
                              hipStream_t stream) {
    const float* x  = (const float*)d_in[0];
    const int*   ei = (const int*)d_in[1];
    const float* ev = (const float*)d_in[2];
    const float* W1 = (const float*)d_in[3];
    const float* W2 = (const float*)d_in[4];
    const float* W3 = (const float*)d_in[5];
    float* out = (float*)d_out;

    char* ws = (char*)d_ws;
    size_t o = 0;
    unsigned short* B1 = (unsigned short*)(ws + o); o += (size_t)NN * FD * 2;   // 51.2 MB agg (aliases ebuf)
    u32*   Q8          = (u32*)(ws + o);            o += (size_t)NN * FD;       // 25.6 MB int8 table
    float* Sc          = (float*)(ws + o);          o += (size_t)NN * 4;        // 400 KB scales
    unsigned short* Lb = (unsigned short*)(ws + o); o += (size_t)NN * NC * 2;   // 8 MB
    int2*  cp          = (int2*)(ws + o);           o += (size_t)NE * 8;        // 25.6 MB
    int*   row_ptr     = (int*)(ws + o);            o += 400128;
    int*   gcount      = (int*)(ws + o);            o += 1024;
    int*   bucketBase  = (int*)(ws + o);            o += 1024;
    int*   bucketFill  = (int*)(ws + o);            o += 1024;
    unsigned short* Wt1  = (unsigned short*)(ws + o); o += 256 * 256 * 2;
    unsigned short* Wt2  = (unsigned short*)(ws + o); o += 256 * 256 * 2;
    unsigned short* Wt3p = (unsigned short*)(ws + o); o += 48 * 256 * 2;

    int2* ebuf = (int2*)B1;   // lifetime: partition_edges..bucket_csr, before B1's first write

    const int EB8   = (NE + 8191) / 8192;         // 391 (8192 edges/block, chunk-guarded)
    const int RGRID = (NN + 3) / 4;               // 25000
    const int GXM   = (NN + BM - 1) / BM;         // 782

    // binned CSR build
    hipMemsetAsync(gcount, 0, BN_BUCK * sizeof(int), stream);
    bucket_count<<<EB8, 256, 0, stream>>>(ei + NE, gcount);
    bucket_scan<<<1, 256, 0, stream>>>(gcount, bucketBase, bucketFill, row_ptr);
    partition_edges<<<EB8, 256, 0, stream>>>(ei, ev, bucketFill, ebuf);
    bucket_csr<<<BN_BUCK, 512, 0, stream>>>(bucketBase, ebuf, row_ptr, cp);

    // prep (merged): x -> int8 + scales, weights transposed bf16
    prep<<<25560, 256, 0, stream>>>(x, W1, W2, W3, Q8, Sc, Wt1, Wt2, Wt3p);

    // Layer 1: agg = A @ x (int8 gather) ; Q8/Sc = uint8-quant(relu(agg @ W1)) fused
    spmm_i8<0><<<RGRID, 256, 0, stream>>>(row_ptr, cp, Q8, Sc, B1);
    gemm1_quant<<<GXM, 256, 0, stream>>>(B1, Wt1, (unsigned char*)Q8, Sc, NN);

    // Layer 2+3 fused: agg = A @ h1 (uint8 gather) ; Lb = relu(agg @ W2) @ W3 (h2 in LDS only)
    spmm_i8<1><<<RGRID, 256, 0, stream>>>(row_ptr, cp, Q8, Sc, B1);
    gemm23<<<GXM, 256, 0, stream>>>(B1, Wt2, Wt3p, Lb, NN);

    // final: out = log_softmax( A @ Lb )
    spmm40_lsm<<<RGRID, 256, 0, stream>>>(row_ptr, cp, Lb, out);
}